// Round 2
// baseline (9874.989 us; speedup 1.0000x reference)
//
#include <hip/hip_runtime.h>

typedef __bf16 bf16x8 __attribute__((ext_vector_type(8)));
typedef __bf16 bf16x2 __attribute__((ext_vector_type(2)));
typedef float  f32x4  __attribute__((ext_vector_type(4)));
typedef unsigned short u16;

// ---------------- constants ----------------
#define BATCH   8192
#define NTOK    4
#define ROWS    (BATCH*NTOK)      // 32768
#define DIM     512
#define HEADS   8
#define DH      64
#define FFI     2048              // FF_INNER
#define DEPTH   12
#define LN_EPS  1e-5f

// ---------------- workspace layout (bytes) ----------------
static const size_t OFF_WTQ  = 0;
static const size_t SZ_WTQ   = 12ull*512*512*2;
static const size_t OFF_WTKV = OFF_WTQ + SZ_WTQ;
static const size_t SZ_WTKV  = 12ull*128*512*2;
static const size_t OFF_WTO  = OFF_WTKV + SZ_WTKV;
static const size_t SZ_WTO   = SZ_WTQ;
static const size_t OFF_WTF1 = OFF_WTO + SZ_WTO;
static const size_t SZ_WTF1  = 12ull*4096*512*2;
static const size_t OFF_WTF2 = OFF_WTF1 + SZ_WTF1;
static const size_t SZ_WTF2  = 12ull*512*2048*2;
static const size_t OFF_WTP  = OFF_WTF2 + SZ_WTF2;
static const size_t SZ_WTP   = 512ull*512*2;
static const size_t OFF_X    = OFF_WTP + SZ_WTP;               // f32 (32768,512)
static const size_t OFF_H    = OFF_X    + (size_t)ROWS*DIM*4;
static const size_t OFF_QRAW = OFF_H    + (size_t)ROWS*DIM*2;  // also Y (Wo output)
static const size_t OFF_KV   = OFF_QRAW + (size_t)ROWS*DIM*2;
static const size_t OFF_AO   = OFF_KV   + (size_t)ROWS*128*2;  // attn_out / ffact chunk / hlast
static const size_t OFF_FLAG = OFF_AO   + (size_t)ROWS*DIM*2;
static const size_t WS_NEED  = OFF_FLAG + 256;                 // 266,338,560 B

// ---------------- helpers ----------------
// dual-dtype input read: element i of a device input tensor
__device__ __forceinline__ float ldf(const void* p, size_t i, bool b16) {
  return b16 ? (float)((const __bf16*)p)[i] : ((const float*)p)[i];
}

__device__ __forceinline__ float wave_sum(float v) {
  #pragma unroll
  for (int o = 32; o > 0; o >>= 1) v += __shfl_xor(v, o, 64);
  return v;
}

// 256-thread block reduce of (a,b)
__device__ __forceinline__ void block_reduce2(float& a, float& b, float* sm) {
  #pragma unroll
  for (int o = 32; o > 0; o >>= 1) { a += __shfl_down(a, o, 64); b += __shfl_down(b, o, 64); }
  int lane = threadIdx.x & 63, w = threadIdx.x >> 6;
  if (lane == 0) { sm[w] = a; sm[4+w] = b; }
  __syncthreads();
  a = sm[0]+sm[1]+sm[2]+sm[3];
  b = sm[4]+sm[5]+sm[6]+sm[7];
}

// ---------------- dtype detection: 1 block, writes flag (1 = bf16, 0 = fp32) ----------------
__global__ void detect_dtype(const unsigned int* __restrict__ w, int* __restrict__ flag) {
  __shared__ int cnt[4];
  int t = threadIdx.x;
  int c = 0;
  for (int i = t; i < 2048; i += 256) {
    unsigned int v = w[i];
    unsigned int lo = v & 0xFFFFu, hi = v >> 16;
    int elo = (int)((lo >> 7) & 0xFF), ehi = (int)((hi >> 7) & 0xFF);
    bool okl = (lo == 0u) || (elo >= 100 && elo <= 140);
    bool okh = (hi == 0u) || (ehi >= 100 && ehi <= 140);
    if (okl && okh) c++;
  }
  #pragma unroll
  for (int o = 32; o > 0; o >>= 1) c += __shfl_down(c, o, 64);
  if ((t & 63) == 0) cnt[t >> 6] = c;
  __syncthreads();
  if (t == 0) flag[0] = (cnt[0] + cnt[1] + cnt[2] + cnt[3] > 1024) ? 1 : 0;
}

// ---------------- weight transpose (K,N)->(N,K) with dtype conversion, batched over Z ----------------
__global__ void transpose_any(const void* __restrict__ in, u16* __restrict__ out,
                              int K, int N, const int* __restrict__ flag) {
  bool b16 = flag[0] != 0;
  __shared__ u16 tile[32][33];
  size_t boff = (size_t)blockIdx.z * K * N;
  int n0 = blockIdx.x * 32, k0 = blockIdx.y * 32;
  int tx = threadIdx.x, ty = threadIdx.y;
  #pragma unroll
  for (int r = 0; r < 4; r++) {
    float v = ldf(in, boff + (size_t)(k0 + ty*4 + r) * N + n0 + tx, b16);
    __bf16 bv = (__bf16)v;
    tile[ty*4+r][tx] = __builtin_bit_cast(u16, bv);
  }
  __syncthreads();
  #pragma unroll
  for (int r = 0; r < 4; r++)
    out[boff + (size_t)(n0 + ty*4 + r) * K + k0 + tx] = tile[tx][ty*4+r];
}

// ---------------- token assembly: x (B,4,512) f32 ----------------
__global__ void build_tokens(const void* __restrict__ text, const void* __restrict__ img,
                             const int* __restrict__ ts, const void* __restrict__ table,
                             const void* __restrict__ lq, float* __restrict__ x,
                             const int* __restrict__ flag) {
  bool b16 = flag[0] != 0;
  int b = blockIdx.x, t = threadIdx.x;
  float* xr = x + (size_t)b * NTOK * DIM;
  int tsb = ts[b];
  for (int e = t; e < DIM; e += 256) {
    xr[e]         = ldf(text,  (size_t)b * DIM + e, b16);
    xr[DIM + e]   = ldf(table, (size_t)tsb * DIM + e, b16);
    xr[2*DIM + e] = ldf(img,   (size_t)b * DIM + e, b16);
    xr[3*DIM + e] = ldf(lq,    (size_t)e, b16);
  }
}

// ---------------- LN: f32 row -> bf16 row ----------------
__global__ void ln_f32_bf16(const float* __restrict__ x, const void* __restrict__ g, size_t goff,
                            __bf16* __restrict__ out, const int* __restrict__ flag) {
  bool b16 = flag[0] != 0;
  __shared__ float sm[8];
  int row = blockIdx.x, t = threadIdx.x;
  float2 v = ((const float2*)(x + (size_t)row * DIM))[t];
  float s = v.x + v.y, s2 = v.x*v.x + v.y*v.y;
  block_reduce2(s, s2, sm);
  float mean = s * (1.f/DIM);
  float var  = s2 * (1.f/DIM) - mean*mean;
  float rs = rsqrtf(var + LN_EPS);
  float g0 = ldf(g, goff + 2*t, b16), g1 = ldf(g, goff + 2*t + 1, b16);
  bf16x2 o2 = { (__bf16)((v.x-mean)*rs*g0), (__bf16)((v.y-mean)*rs*g1) };
  ((bf16x2*)(out + (size_t)row * DIM))[t] = o2;
}

// ---------------- x += LN(y) ----------------
__global__ void ln_add(const __bf16* __restrict__ y, const void* __restrict__ g, size_t goff,
                       float* __restrict__ x, const int* __restrict__ flag) {
  bool b16 = flag[0] != 0;
  __shared__ float sm[8];
  int row = blockIdx.x, t = threadIdx.x;
  bf16x2 yv = ((const bf16x2*)(y + (size_t)row * DIM))[t];
  float v0 = (float)yv[0], v1 = (float)yv[1];
  float s = v0 + v1, s2 = v0*v0 + v1*v1;
  block_reduce2(s, s2, sm);
  float mean = s * (1.f/DIM);
  float var  = s2 * (1.f/DIM) - mean*mean;
  float rs = rsqrtf(var + LN_EPS);
  float g0 = ldf(g, goff + 2*t, b16), g1 = ldf(g, goff + 2*t + 1, b16);
  float2* xr = (float2*)(x + (size_t)row * DIM);
  float2 xv = xr[t];
  xv.x += (v0-mean)*rs*g0;
  xv.y += (v1-mean)*rs*g1;
  xr[t] = xv;
}

// ---------------- final LN on token 3 rows -> hlast (8192,512) bf16 ----------------
__global__ void ln_final(const float* __restrict__ x, const void* __restrict__ g,
                         __bf16* __restrict__ out, const int* __restrict__ flag) {
  bool b16 = flag[0] != 0;
  __shared__ float sm[8];
  int b = blockIdx.x, t = threadIdx.x;
  int row = b*NTOK + 3;
  float2 v = ((const float2*)(x + (size_t)row * DIM))[t];
  float s = v.x + v.y, s2 = v.x*v.x + v.y*v.y;
  block_reduce2(s, s2, sm);
  float mean = s * (1.f/DIM);
  float var  = s2 * (1.f/DIM) - mean*mean;
  float rs = rsqrtf(var + LN_EPS);
  float g0 = ldf(g, (size_t)2*t, b16), g1 = ldf(g, (size_t)2*t + 1, b16);
  bf16x2 o2 = { (__bf16)((v.x-mean)*rs*g0), (__bf16)((v.y-mean)*rs*g1) };
  ((bf16x2*)(out + (size_t)b * DIM))[t] = o2;
}

// ---------------- GEMM: C(M,N) = A(M,K) @ Bt(N,K)^T, 128x128 tile, BK=32 ----------------
// MODE 0: store bf16. MODE 1: accumulate f32. MODE 2: store bf16 or f32 per flag.
template<int MODE>
__global__ __launch_bounds__(256) void gemm_bt(
    const __bf16* __restrict__ A, int lda,
    const __bf16* __restrict__ B, int ldb,
    void* __restrict__ Cv, int ldc, int K, const int* __restrict__ flag)
{
  __shared__ __bf16 As[128*32];
  __shared__ __bf16 Bs[128*32];
  const int tid = threadIdx.x;
  const int wave = tid >> 6, lane = tid & 63;
  const int wr = wave >> 1, wc = wave & 1;
  const __bf16* Ab = A + (size_t)blockIdx.y * 128 * lda;
  const __bf16* Bb = B + (size_t)blockIdx.x * 128 * ldb;
  f32x4 acc[4][4] = {};
  const int r = tid >> 2, cg = (tid & 3) * 8;
  const int lr = lane & 15, lk = (lane >> 4) * 8;
  for (int k0 = 0; k0 < K; k0 += 32) {
    bf16x8 a0 = *(const bf16x8*)(Ab + (size_t)r*lda      + k0 + cg);
    bf16x8 a1 = *(const bf16x8*)(Ab + (size_t)(r+64)*lda + k0 + cg);
    bf16x8 b0 = *(const bf16x8*)(Bb + (size_t)r*ldb      + k0 + cg);
    bf16x8 b1 = *(const bf16x8*)(Bb + (size_t)(r+64)*ldb + k0 + cg);
    __syncthreads();   // prev iteration's fragment reads complete
    *(bf16x8*)(As + r*32      + cg) = a0;
    *(bf16x8*)(As + (r+64)*32 + cg) = a1;
    *(bf16x8*)(Bs + r*32      + cg) = b0;
    *(bf16x8*)(Bs + (r+64)*32 + cg) = b1;
    __syncthreads();   // tile fully staged
    bf16x8 af[4], bq[4];
    #pragma unroll
    for (int m = 0; m < 4; m++) af[m] = *(const bf16x8*)(As + (wr*64 + m*16 + lr)*32 + lk);
    #pragma unroll
    for (int n = 0; n < 4; n++) bq[n] = *(const bf16x8*)(Bs + (wc*64 + n*16 + lr)*32 + lk);
    #pragma unroll
    for (int m = 0; m < 4; m++)
      #pragma unroll
      for (int n = 0; n < 4; n++)
        acc[m][n] = __builtin_amdgcn_mfma_f32_16x16x32_bf16(af[m], bq[n], acc[m][n], 0, 0, 0);
  }
  const int row0 = blockIdx.y*128 + wr*64 + (lane >> 4)*4;
  const int col0 = blockIdx.x*128 + wc*64 + (lane & 15);
  if (MODE == 0) {
    __bf16* Cb = (__bf16*)Cv;
    #pragma unroll
    for (int m = 0; m < 4; m++)
      #pragma unroll
      for (int rr = 0; rr < 4; rr++) {
        size_t ro = (size_t)(row0 + m*16 + rr) * ldc + col0;
        #pragma unroll
        for (int n = 0; n < 4; n++) Cb[ro + n*16] = (__bf16)acc[m][n][rr];
      }
  } else if (MODE == 1) {
    float* Xf = (float*)Cv;
    #pragma unroll
    for (int m = 0; m < 4; m++)
      #pragma unroll
      for (int rr = 0; rr < 4; rr++) {
        size_t ro = (size_t)(row0 + m*16 + rr) * ldc + col0;
        #pragma unroll
        for (int n = 0; n < 4; n++) Xf[ro + n*16] += acc[m][n][rr];
      }
  } else {
    bool b16o = flag[0] != 0;
    __bf16* Cb = (__bf16*)Cv;
    float*  Cf = (float*)Cv;
    #pragma unroll
    for (int m = 0; m < 4; m++)
      #pragma unroll
      for (int rr = 0; rr < 4; rr++) {
        size_t ro = (size_t)(row0 + m*16 + rr) * ldc + col0;
        #pragma unroll
        for (int n = 0; n < 4; n++) {
          float val = acc[m][n][rr];
          if (b16o) Cb[ro + n*16] = (__bf16)val; else Cf[ro + n*16] = val;
        }
      }
  }
}

// ---------------- fused SwiGLU GEMM: out = (A@Ba^T) * silu(A@Bg^T), bf16 ----------------
__global__ __launch_bounds__(256) void gemm_swiglu(
    const __bf16* __restrict__ A, int lda,
    const __bf16* __restrict__ Ba, const __bf16* __restrict__ Bg, int ldb,
    __bf16* __restrict__ Out, int ldc, int K)
{
  __shared__ __bf16 As[128*32];
  __shared__ __bf16 Bsa[128*32];
  __shared__ __bf16 Bsg[128*32];
  const int tid = threadIdx.x;
  const int wave = tid >> 6, lane = tid & 63;
  const int wr = wave >> 1, wc = wave & 1;
  const __bf16* Ab  = A  + (size_t)blockIdx.y * 128 * lda;
  const __bf16* Bab = Ba + (size_t)blockIdx.x * 128 * ldb;
  const __bf16* Bgb = Bg + (size_t)blockIdx.x * 128 * ldb;
  f32x4 aca[4][4] = {};
  f32x4 acg[4][4] = {};
  const int r = tid >> 2, cg = (tid & 3) * 8;
  const int lr = lane & 15, lk = (lane >> 4) * 8;
  for (int k0 = 0; k0 < K; k0 += 32) {
    bf16x8 a0 = *(const bf16x8*)(Ab  + (size_t)r*lda      + k0 + cg);
    bf16x8 a1 = *(const bf16x8*)(Ab  + (size_t)(r+64)*lda + k0 + cg);
    bf16x8 p0 = *(const bf16x8*)(Bab + (size_t)r*ldb      + k0 + cg);
    bf16x8 p1 = *(const bf16x8*)(Bab + (size_t)(r+64)*ldb + k0 + cg);
    bf16x8 q0 = *(const bf16x8*)(Bgb + (size_t)r*ldb      + k0 + cg);
    bf16x8 q1 = *(const bf16x8*)(Bgb + (size_t)(r+64)*ldb + k0 + cg);
    __syncthreads();
    *(bf16x8*)(As  + r*32      + cg) = a0;
    *(bf16x8*)(As  + (r+64)*32 + cg) = a1;
    *(bf16x8*)(Bsa + r*32      + cg) = p0;
    *(bf16x8*)(Bsa + (r+64)*32 + cg) = p1;
    *(bf16x8*)(Bsg + r*32      + cg) = q0;
    *(bf16x8*)(Bsg + (r+64)*32 + cg) = q1;
    __syncthreads();
    bf16x8 af[4], ba[4], bg[4];
    #pragma unroll
    for (int m = 0; m < 4; m++) af[m] = *(const bf16x8*)(As  + (wr*64 + m*16 + lr)*32 + lk);
    #pragma unroll
    for (int n = 0; n < 4; n++) ba[n] = *(const bf16x8*)(Bsa + (wc*64 + n*16 + lr)*32 + lk);
    #pragma unroll
    for (int n = 0; n < 4; n++) bg[n] = *(const bf16x8*)(Bsg + (wc*64 + n*16 + lr)*32 + lk);
    #pragma unroll
    for (int m = 0; m < 4; m++)
      #pragma unroll
      for (int n = 0; n < 4; n++) {
        aca[m][n] = __builtin_amdgcn_mfma_f32_16x16x32_bf16(af[m], ba[n], aca[m][n], 0, 0, 0);
        acg[m][n] = __builtin_amdgcn_mfma_f32_16x16x32_bf16(af[m], bg[n], acg[m][n], 0, 0, 0);
      }
  }
  const int row0 = blockIdx.y*128 + wr*64 + (lane >> 4)*4;
  const int col0 = blockIdx.x*128 + wc*64 + (lane & 15);
  #pragma unroll
  for (int m = 0; m < 4; m++)
    #pragma unroll
    for (int rr = 0; rr < 4; rr++) {
      size_t ro = (size_t)(row0 + m*16 + rr) * ldc + col0;
      #pragma unroll
      for (int n = 0; n < 4; n++) {
        float av = aca[m][n][rr], gv = acg[m][n][rr];
        Out[ro + n*16] = (__bf16)(av * gv / (1.f + __expf(-gv)));
      }
    }
}

// ---------------- fused attention: one wave per (b, h) ----------------
__global__ __launch_bounds__(256) void attn_kernel(
    const __bf16* __restrict__ qraw, const __bf16* __restrict__ kvraw,
    const void* __restrict__ nkv_all, int layer, const void* __restrict__ rel_emb,
    __bf16* __restrict__ ao, const int* __restrict__ flag)
{
  bool b16 = flag[0] != 0;
  int gw = blockIdx.x * 4 + (threadIdx.x >> 6);
  int lane = threadIdx.x & 63;
  int b = gw >> 3, h = gw & 7;
  int d = lane;
  bool rot = d < 32;
  int j2 = d >> 1;
  float inv = __expf(-(float)(2*j2) * (1.f/32.f) * 9.210340371976184f); // ln(10000)

  // q rows: rotary + l2norm (SCALE cancels under l2norm)
  float q[4];
  #pragma unroll
  for (int i = 0; i < 4; i++) {
    float v = (float)qraw[((size_t)(b*NTOK + i)) * DIM + h*DH + d];
    float p = __shfl_xor(v, 1, 64);
    if (rot) {
      float sn, cs; __sincosf((float)i * inv, &sn, &cs);
      v = (d & 1) ? (v*cs + p*sn) : (v*cs - p*sn);
    }
    q[i] = v;
  }
  #pragma unroll
  for (int i = 0; i < 4; i++) {
    float nrm = sqrtf(wave_sum(q[i]*q[i]));
    q[i] = q[i] / fmaxf(nrm, 1e-12f);
  }

  // k (null + 4, rotary on real keys, l2norm on all) and v (null + 4)
  float kk[5], vv[5];
  kk[0] = ldf(nkv_all, (size_t)layer*128 + d, b16);
  vv[0] = ldf(nkv_all, (size_t)layer*128 + 64 + d, b16);
  #pragma unroll
  for (int j = 1; j < 5; j++) {
    const __bf16* base = kvraw + ((size_t)(b*NTOK + j - 1)) * 128;
    float v = (float)base[d];
    vv[j] = (float)base[64 + d];
    float p = __shfl_xor(v, 1, 64);
    if (rot) {
      float sn, cs; __sincosf((float)(j-1) * inv, &sn, &cs);
      v = (d & 1) ? (v*cs + p*sn) : (v*cs - p*sn);
    }
    kk[j] = v;
  }
  #pragma unroll
  for (int j = 0; j < 5; j++) {
    float nrm = sqrtf(wave_sum(kk[j]*kk[j]));
    kk[j] = kk[j] / fmaxf(nrm, 1e-12f);
  }

  // sim (only unmasked j <= i+1), * SCALE(16), + bias; softmax; out = attn @ v
  #pragma unroll
  for (int i = 0; i < 4; i++) {
    float sim[5];
    #pragma unroll
    for (int j = 0; j < 5; j++) {
      if (j > i + 1) break;
      float p = wave_sum(q[i] * kk[j]);
      sim[j] = p * 16.f + ldf(rel_emb, (size_t)(i - j > 0 ? i - j : 0) * 8 + h, b16);
    }
    float m = sim[0];
    #pragma unroll
    for (int j = 1; j < 5; j++) { if (j > i + 1) break; m = fmaxf(m, sim[j]); }
    float Z = 0.f, o = 0.f;
    #pragma unroll
    for (int j = 0; j < 5; j++) {
      if (j > i + 1) break;
      float e = __expf(sim[j] - m);
      Z += e; o += e * vv[j];
    }
    ao[((size_t)(b*NTOK + i)) * DIM + h*DH + d] = (__bf16)(o / Z);
  }
}

// ---------------- launch ----------------
extern "C" void kernel_launch(void* const* d_in, const int* in_sizes, int n_in,
                              void* d_out, int out_size, void* d_ws, size_t ws_size,
                              hipStream_t stream) {
  const void* image_embed     = d_in[0];
  const void* text_embed      = d_in[1];
  const int*  timesteps       = (const int*)d_in[2];
  const void* time_table      = d_in[3];
  const void* learned_query   = d_in[4];
  const void* rel_emb         = d_in[5];
  const void* attn_norm_g     = d_in[6];
  const void* Wq              = d_in[7];
  const void* Wkv             = d_in[8];
  const void* null_kv         = d_in[9];
  const void* Wo              = d_in[10];
  const void* attn_out_norm_g = d_in[11];
  const void* ff_norm_g       = d_in[12];
  const void* Wff1            = d_in[13];
  const void* Wff2            = d_in[14];
  const void* final_norm_g    = d_in[15];
  const void* Wproj           = d_in[16];

  if (ws_size < WS_NEED) return;  // insufficient workspace -> visible clean failure

  char* ws = (char*)d_ws;
  __bf16* wtq  = (__bf16*)(ws + OFF_WTQ);
  __bf16* wtkv = (__bf16*)(ws + OFF_WTKV);
  __bf16* wto  = (__bf16*)(ws + OFF_WTO);
  __bf16* wtf1 = (__bf16*)(ws + OFF_WTF1);
  __bf16* wtf2 = (__bf16*)(ws + OFF_WTF2);
  __bf16* wtp  = (__bf16*)(ws + OFF_WTP);
  float*  x    = (float*) (ws + OFF_X);
  __bf16* h    = (__bf16*)(ws + OFF_H);
  __bf16* qraw = (__bf16*)(ws + OFF_QRAW);  // also y
  __bf16* kvraw= (__bf16*)(ws + OFF_KV);
  __bf16* ao   = (__bf16*)(ws + OFF_AO);    // attn_out / ffact chunk / hlast
  int*    flag = (int*)   (ws + OFF_FLAG);

  detect_dtype<<<1, 256, 0, stream>>>((const unsigned int*)Wq, flag);

  dim3 tb(32, 8);
  transpose_any<<<dim3(16, 16, 12),  tb, 0, stream>>>(Wq,   (u16*)wtq,  512,  512,  flag);
  transpose_any<<<dim3(4,  16, 12),  tb, 0, stream>>>(Wkv,  (u16*)wtkv, 512,  128,  flag);
  transpose_any<<<dim3(16, 16, 12),  tb, 0, stream>>>(Wo,   (u16*)wto,  512,  512,  flag);
  transpose_any<<<dim3(128,16, 12),  tb, 0, stream>>>(Wff1, (u16*)wtf1, 512,  4096, flag);
  transpose_any<<<dim3(16, 64, 12),  tb, 0, stream>>>(Wff2, (u16*)wtf2, 2048, 512,  flag);
  transpose_any<<<dim3(16, 16, 1),   tb, 0, stream>>>(Wproj,(u16*)wtp,  512,  512,  flag);

  build_tokens<<<BATCH, 256, 0, stream>>>(text_embed, image_embed, timesteps, time_table,
                                          learned_query, x, flag);

  for (int l = 0; l < DEPTH; l++) {
    const __bf16* wtq_l  = wtq  + (size_t)l * 512 * 512;
    const __bf16* wtkv_l = wtkv + (size_t)l * 128 * 512;
    const __bf16* wto_l  = wto  + (size_t)l * 512 * 512;
    const __bf16* wtf1_l = wtf1 + (size_t)l * 4096 * 512;
    const __bf16* wtf2_l = wtf2 + (size_t)l * 512 * 2048;

    ln_f32_bf16<<<ROWS, 256, 0, stream>>>(x, attn_norm_g, (size_t)l*DIM, h, flag);
    gemm_bt<0><<<dim3(4, ROWS/128), 256, 0, stream>>>(h, DIM, wtq_l, 512, qraw, DIM, 512, flag);
    gemm_bt<0><<<dim3(1, ROWS/128), 256, 0, stream>>>(h, DIM, wtkv_l, 512, kvraw, 128, 512, flag);
    attn_kernel<<<BATCH*HEADS/4, 256, 0, stream>>>(qraw, kvraw, null_kv, l, rel_emb, ao, flag);
    gemm_bt<0><<<dim3(4, ROWS/128), 256, 0, stream>>>(ao, DIM, wto_l, 512, qraw /*y*/, DIM, 512, flag);
    ln_add<<<ROWS, 256, 0, stream>>>(qraw /*y*/, attn_out_norm_g, (size_t)l*DIM, x, flag);
    ln_f32_bf16<<<ROWS, 256, 0, stream>>>(x, ff_norm_g, (size_t)l*DIM, h, flag);
    // FF in 4 column-chunks of 512 (ffact aliases ao region)
    for (int c = 0; c < 4; c++) {
      const __bf16* ba = wtf1_l + (size_t)(c*512) * 512;
      const __bf16* bg = wtf1_l + (size_t)(FFI + c*512) * 512;
      gemm_swiglu<<<dim3(4, ROWS/128), 256, 0, stream>>>(h, DIM, ba, bg, 512, ao, 512, 512);
      gemm_bt<1><<<dim3(4, ROWS/128), 256, 0, stream>>>(ao, 512, wtf2_l + c*512, 2048, x, DIM, 512, flag);
    }
  }

  ln_final<<<BATCH, 256, 0, stream>>>(x, final_norm_g, ao /*hlast*/, flag);
  gemm_bt<2><<<dim3(4, BATCH/128), 256, 0, stream>>>(ao, DIM, wtp, 512, d_out, DIM, 512, flag);
}

// Round 3
// 8584.200 us; speedup vs baseline: 1.1504x; 1.1504x over previous
//
#include <hip/hip_runtime.h>

typedef __bf16 bf16x8 __attribute__((ext_vector_type(8)));
typedef __bf16 bf16x2 __attribute__((ext_vector_type(2)));
typedef float  f32x4  __attribute__((ext_vector_type(4)));
typedef unsigned short u16;

// ---------------- constants ----------------
#define BATCH   8192
#define NTOK    4
#define ROWS    (BATCH*NTOK)      // 32768
#define DIM     512
#define HEADS   8
#define DH      64
#define FFI     2048              // FF_INNER
#define DEPTH   12
#define LN_EPS  1e-5f

// ---------------- workspace layout (bytes) ----------------
static const size_t OFF_WTQ  = 0;
static const size_t SZ_WTQ   = 12ull*512*512*2;
static const size_t OFF_WTKV = OFF_WTQ + SZ_WTQ;
static const size_t SZ_WTKV  = 12ull*128*512*2;
static const size_t OFF_WTO  = OFF_WTKV + SZ_WTKV;
static const size_t SZ_WTO   = SZ_WTQ;
static const size_t OFF_WTF1 = OFF_WTO + SZ_WTO;
static const size_t SZ_WTF1  = 12ull*4096*512*2;
static const size_t OFF_WTF2 = OFF_WTF1 + SZ_WTF1;
static const size_t SZ_WTF2  = 12ull*512*2048*2;
static const size_t OFF_WTP  = OFF_WTF2 + SZ_WTF2;
static const size_t SZ_WTP   = 512ull*512*2;
static const size_t OFF_X    = OFF_WTP + SZ_WTP;               // f32 (32768,512)
static const size_t OFF_H    = OFF_X    + (size_t)ROWS*DIM*4;
static const size_t OFF_QRAW = OFF_H    + (size_t)ROWS*DIM*2;  // also Y; also act[0:33.5MB]
static const size_t OFF_KV   = OFF_QRAW + (size_t)ROWS*DIM*2;  // act cont'd
static const size_t OFF_AO   = OFF_KV   + (size_t)ROWS*128*2;  // attn_out / act cont'd / hlast
static const size_t OFF_FLAG = OFF_AO   + (size_t)ROWS*DIM*2;
static const size_t WS_NEED  = OFF_FLAG + 256;                 // 266,338,560 B
// act buffer (16384 x 2048 bf16 = 67,108,864 B) aliases [OFF_QRAW, OFF_QRAW+67MB)
// which spans qraw(33.5M)+kv(8.4M)+ao(33.5M) = 75.5MB of dead-after-attn space. OK.

// ---------------- helpers ----------------
__device__ __forceinline__ float ldf(const void* p, size_t i, bool b16) {
  return b16 ? (float)((const __bf16*)p)[i] : ((const float*)p)[i];
}

__device__ __forceinline__ void gld_lds16(const void* g, void* l) {
  __builtin_amdgcn_global_load_lds((const __attribute__((address_space(1))) void*)g,
                                   (__attribute__((address_space(3))) void*)l, 16, 0, 0);
}

__device__ __forceinline__ float wave_sum(float v) {
  #pragma unroll
  for (int o = 32; o > 0; o >>= 1) v += __shfl_xor(v, o, 64);
  return v;
}

// 256-thread block reduce of (a,b); barrier-balanced so it is safe to call twice
__device__ __forceinline__ void block_reduce2(float& a, float& b, float* sm) {
  #pragma unroll
  for (int o = 32; o > 0; o >>= 1) { a += __shfl_down(a, o, 64); b += __shfl_down(b, o, 64); }
  int lane = threadIdx.x & 63, w = threadIdx.x >> 6;
  __syncthreads();                       // protect sm against previous use
  if (lane == 0) { sm[w] = a; sm[4+w] = b; }
  __syncthreads();
  a = sm[0]+sm[1]+sm[2]+sm[3];
  b = sm[4]+sm[5]+sm[6]+sm[7];
}

// ---------------- dtype detection: 1 block, writes flag (1 = bf16, 0 = fp32) ----------------
__global__ void detect_dtype(const unsigned int* __restrict__ w, int* __restrict__ flag) {
  __shared__ int cnt[4];
  int t = threadIdx.x;
  int c = 0;
  for (int i = t; i < 2048; i += 256) {
    unsigned int v = w[i];
    unsigned int lo = v & 0xFFFFu, hi = v >> 16;
    int elo = (int)((lo >> 7) & 0xFF), ehi = (int)((hi >> 7) & 0xFF);
    bool okl = (lo == 0u) || (elo >= 100 && elo <= 140);
    bool okh = (hi == 0u) || (ehi >= 100 && ehi <= 140);
    if (okl && okh) c++;
  }
  #pragma unroll
  for (int o = 32; o > 0; o >>= 1) c += __shfl_down(c, o, 64);
  if ((t & 63) == 0) cnt[t >> 6] = c;
  __syncthreads();
  if (t == 0) flag[0] = (cnt[0] + cnt[1] + cnt[2] + cnt[3] > 1024) ? 1 : 0;
}

// ---------------- weight transpose (K,N)->(N,K) with dtype conversion, batched over Z ----------------
__global__ void transpose_any(const void* __restrict__ in, u16* __restrict__ out,
                              int K, int N, const int* __restrict__ flag) {
  bool b16 = flag[0] != 0;
  __shared__ u16 tile[32][33];
  size_t boff = (size_t)blockIdx.z * K * N;
  int n0 = blockIdx.x * 32, k0 = blockIdx.y * 32;
  int tx = threadIdx.x, ty = threadIdx.y;
  #pragma unroll
  for (int r = 0; r < 4; r++) {
    float v = ldf(in, boff + (size_t)(k0 + ty*4 + r) * N + n0 + tx, b16);
    __bf16 bv = (__bf16)v;
    tile[ty*4+r][tx] = __builtin_bit_cast(u16, bv);
  }
  __syncthreads();
  #pragma unroll
  for (int r = 0; r < 4; r++)
    out[boff + (size_t)(n0 + ty*4 + r) * K + k0 + tx] = tile[tx][ty*4+r];
}

// ---------------- token assembly: x (B,4,512) f32 ----------------
__global__ void build_tokens(const void* __restrict__ text, const void* __restrict__ img,
                             const int* __restrict__ ts, const void* __restrict__ table,
                             const void* __restrict__ lq, float* __restrict__ x,
                             const int* __restrict__ flag) {
  bool b16 = flag[0] != 0;
  int b = blockIdx.x, t = threadIdx.x;
  float* xr = x + (size_t)b * NTOK * DIM;
  int tsb = ts[b];
  for (int e = t; e < DIM; e += 256) {
    xr[e]         = ldf(text,  (size_t)b * DIM + e, b16);
    xr[DIM + e]   = ldf(table, (size_t)tsb * DIM + e, b16);
    xr[2*DIM + e] = ldf(img,   (size_t)b * DIM + e, b16);
    xr[3*DIM + e] = ldf(lq,    (size_t)e, b16);
  }
}

// ---------------- LN: f32 row -> bf16 row ----------------
__global__ void ln_f32_bf16(const float* __restrict__ x, const void* __restrict__ g, size_t goff,
                            __bf16* __restrict__ out, const int* __restrict__ flag) {
  bool b16 = flag[0] != 0;
  __shared__ float sm[8];
  int row = blockIdx.x, t = threadIdx.x;
  float2 v = ((const float2*)(x + (size_t)row * DIM))[t];
  float s = v.x + v.y, s2 = v.x*v.x + v.y*v.y;
  block_reduce2(s, s2, sm);
  float mean = s * (1.f/DIM);
  float var  = s2 * (1.f/DIM) - mean*mean;
  float rs = rsqrtf(var + LN_EPS);
  float g0 = ldf(g, goff + 2*t, b16), g1 = ldf(g, goff + 2*t + 1, b16);
  bf16x2 o2 = { (__bf16)((v.x-mean)*rs*g0), (__bf16)((v.y-mean)*rs*g1) };
  ((bf16x2*)(out + (size_t)row * DIM))[t] = o2;
}

// ---------------- fused: x += LN(y; g1); h = LN(x; g2) ----------------
__global__ void ln_add_ln(const __bf16* __restrict__ y,
                          const void* __restrict__ g1, size_t g1off,
                          const void* __restrict__ g2, size_t g2off,
                          float* __restrict__ x, __bf16* __restrict__ h,
                          const int* __restrict__ flag) {
  bool b16 = flag[0] != 0;
  __shared__ float sm[8];
  int row = blockIdx.x, t = threadIdx.x;
  bf16x2 yv = ((const bf16x2*)(y + (size_t)row * DIM))[t];
  float v0 = (float)yv[0], v1 = (float)yv[1];
  float s = v0 + v1, s2 = v0*v0 + v1*v1;
  block_reduce2(s, s2, sm);
  float mean = s * (1.f/DIM);
  float var  = s2 * (1.f/DIM) - mean*mean;
  float rs = rsqrtf(var + LN_EPS);
  float ga = ldf(g1, g1off + 2*t, b16), gb = ldf(g1, g1off + 2*t + 1, b16);
  float2* xr = (float2*)(x + (size_t)row * DIM);
  float2 xv = xr[t];
  xv.x += (v0-mean)*rs*ga;
  xv.y += (v1-mean)*rs*gb;
  xr[t] = xv;
  // second LN on updated x row (in registers)
  float s_  = xv.x + xv.y, s2_ = xv.x*xv.x + xv.y*xv.y;
  block_reduce2(s_, s2_, sm);
  float mean2 = s_ * (1.f/DIM);
  float var2  = s2_ * (1.f/DIM) - mean2*mean2;
  float rs2 = rsqrtf(var2 + LN_EPS);
  float gc = ldf(g2, g2off + 2*t, b16), gd = ldf(g2, g2off + 2*t + 1, b16);
  bf16x2 o2 = { (__bf16)((xv.x-mean2)*rs2*gc), (__bf16)((xv.y-mean2)*rs2*gd) };
  ((bf16x2*)(h + (size_t)row * DIM))[t] = o2;
}

// ---------------- final LN on token 3 rows -> hlast (8192,512) bf16 ----------------
__global__ void ln_final(const float* __restrict__ x, const void* __restrict__ g,
                         __bf16* __restrict__ out, const int* __restrict__ flag) {
  bool b16 = flag[0] != 0;
  __shared__ float sm[8];
  int b = blockIdx.x, t = threadIdx.x;
  int row = b*NTOK + 3;
  float2 v = ((const float2*)(x + (size_t)row * DIM))[t];
  float s = v.x + v.y, s2 = v.x*v.x + v.y*v.y;
  block_reduce2(s, s2, sm);
  float mean = s * (1.f/DIM);
  float var  = s2 * (1.f/DIM) - mean*mean;
  float rs = rsqrtf(var + LN_EPS);
  float g0 = ldf(g, (size_t)2*t, b16), g1 = ldf(g, (size_t)2*t + 1, b16);
  bf16x2 o2 = { (__bf16)((v.x-mean)*rs*g0), (__bf16)((v.y-mean)*rs*g1) };
  ((bf16x2*)(out + (size_t)b * DIM))[t] = o2;
}

// ---------------- GEMM: C(M,N) = A(M,K) @ Bt(N,K)^T, 128x128 tile, BK=32 ----------------
// global_load_lds staging (m97 structure).
// MODE 0: store bf16. MODE 1: accumulate f32. MODE 2: store bf16 or f32 per flag.
template<int MODE>
__global__ __launch_bounds__(256) void gemm_bt(
    const __bf16* __restrict__ A, int lda,
    const __bf16* __restrict__ B, int ldb,
    void* __restrict__ Cv, int ldc, int K, const int* __restrict__ flag)
{
  __shared__ __bf16 As[128*32];
  __shared__ __bf16 Bs[128*32];
  const int tid = threadIdx.x;
  const int wave = tid >> 6, lane = tid & 63;
  const int wr = wave >> 1, wc = wave & 1;
  const __bf16* Ab = A + (size_t)blockIdx.y * 128 * lda;
  const __bf16* Bb = B + (size_t)blockIdx.x * 128 * ldb;
  f32x4 acc[4][4] = {};
  const int r = tid >> 2, cg = (tid & 3) * 8;     // staging: row r, k-chunk cg
  const int lr = lane & 15, lk = (lane >> 4) * 8; // fragment: row lr, k-off lk
  for (int k0 = 0; k0 < K; k0 += 32) {
    __syncthreads();   // prev iteration's fragment reads complete
    gld_lds16(Ab + (size_t)r*lda      + k0 + cg, (char*)As + wave*1024);
    gld_lds16(Ab + (size_t)(r+64)*lda + k0 + cg, (char*)As + 4096 + wave*1024);
    gld_lds16(Bb + (size_t)r*ldb      + k0 + cg, (char*)Bs + wave*1024);
    gld_lds16(Bb + (size_t)(r+64)*ldb + k0 + cg, (char*)Bs + 4096 + wave*1024);
    __syncthreads();   // vmcnt(0) drain + barrier: tile staged
    bf16x8 af[4], bq[4];
    #pragma unroll
    for (int m = 0; m < 4; m++) af[m] = *(const bf16x8*)(As + (wr*64 + m*16 + lr)*32 + lk);
    #pragma unroll
    for (int n = 0; n < 4; n++) bq[n] = *(const bf16x8*)(Bs + (wc*64 + n*16 + lr)*32 + lk);
    #pragma unroll
    for (int m = 0; m < 4; m++)
      #pragma unroll
      for (int n = 0; n < 4; n++)
        acc[m][n] = __builtin_amdgcn_mfma_f32_16x16x32_bf16(af[m], bq[n], acc[m][n], 0, 0, 0);
  }
  const int row0 = blockIdx.y*128 + wr*64 + (lane >> 4)*4;
  const int col0 = blockIdx.x*128 + wc*64 + (lane & 15);
  if (MODE == 0) {
    __bf16* Cb = (__bf16*)Cv;
    #pragma unroll
    for (int m = 0; m < 4; m++)
      #pragma unroll
      for (int rr = 0; rr < 4; rr++) {
        size_t ro = (size_t)(row0 + m*16 + rr) * ldc + col0;
        #pragma unroll
        for (int n = 0; n < 4; n++) Cb[ro + n*16] = (__bf16)acc[m][n][rr];
      }
  } else if (MODE == 1) {
    float* Xf = (float*)Cv;
    #pragma unroll
    for (int m = 0; m < 4; m++)
      #pragma unroll
      for (int rr = 0; rr < 4; rr++) {
        size_t ro = (size_t)(row0 + m*16 + rr) * ldc + col0;
        #pragma unroll
        for (int n = 0; n < 4; n++) Xf[ro + n*16] += acc[m][n][rr];
      }
  } else {
    bool b16o = flag[0] != 0;
    __bf16* Cb = (__bf16*)Cv;
    float*  Cf = (float*)Cv;
    #pragma unroll
    for (int m = 0; m < 4; m++)
      #pragma unroll
      for (int rr = 0; rr < 4; rr++) {
        size_t ro = (size_t)(row0 + m*16 + rr) * ldc + col0;
        #pragma unroll
        for (int n = 0; n < 4; n++) {
          float val = acc[m][n][rr];
          if (b16o) Cb[ro + n*16] = (__bf16)val; else Cf[ro + n*16] = val;
        }
      }
  }
}

// ---------------- fused SwiGLU GEMM: out = (A@Ba^T) * silu(A@Bg^T), bf16 ----------------
__global__ __launch_bounds__(256) void gemm_swiglu(
    const __bf16* __restrict__ A, int lda,
    const __bf16* __restrict__ Ba, const __bf16* __restrict__ Bg, int ldb,
    __bf16* __restrict__ Out, int ldc, int K)
{
  __shared__ __bf16 As[128*32];
  __shared__ __bf16 Bsa[128*32];
  __shared__ __bf16 Bsg[128*32];
  const int tid = threadIdx.x;
  const int wave = tid >> 6, lane = tid & 63;
  const int wr = wave >> 1, wc = wave & 1;
  const __bf16* Ab  = A  + (size_t)blockIdx.y * 128 * lda;
  const __bf16* Bab = Ba + (size_t)blockIdx.x * 128 * ldb;
  const __bf16* Bgb = Bg + (size_t)blockIdx.x * 128 * ldb;
  f32x4 aca[4][4] = {};
  f32x4 acg[4][4] = {};
  const int r = tid >> 2, cg = (tid & 3) * 8;
  const int lr = lane & 15, lk = (lane >> 4) * 8;
  for (int k0 = 0; k0 < K; k0 += 32) {
    __syncthreads();
    gld_lds16(Ab  + (size_t)r*lda      + k0 + cg, (char*)As  + wave*1024);
    gld_lds16(Ab  + (size_t)(r+64)*lda + k0 + cg, (char*)As  + 4096 + wave*1024);
    gld_lds16(Bab + (size_t)r*ldb      + k0 + cg, (char*)Bsa + wave*1024);
    gld_lds16(Bab + (size_t)(r+64)*ldb + k0 + cg, (char*)Bsa + 4096 + wave*1024);
    gld_lds16(Bgb + (size_t)r*ldb      + k0 + cg, (char*)Bsg + wave*1024);
    gld_lds16(Bgb + (size_t)(r+64)*ldb + k0 + cg, (char*)Bsg + 4096 + wave*1024);
    __syncthreads();
    bf16x8 af[4], ba[4], bg[4];
    #pragma unroll
    for (int m = 0; m < 4; m++) af[m] = *(const bf16x8*)(As  + (wr*64 + m*16 + lr)*32 + lk);
    #pragma unroll
    for (int n = 0; n < 4; n++) ba[n] = *(const bf16x8*)(Bsa + (wc*64 + n*16 + lr)*32 + lk);
    #pragma unroll
    for (int n = 0; n < 4; n++) bg[n] = *(const bf16x8*)(Bsg + (wc*64 + n*16 + lr)*32 + lk);
    #pragma unroll
    for (int m = 0; m < 4; m++)
      #pragma unroll
      for (int n = 0; n < 4; n++) {
        aca[m][n] = __builtin_amdgcn_mfma_f32_16x16x32_bf16(af[m], ba[n], aca[m][n], 0, 0, 0);
        acg[m][n] = __builtin_amdgcn_mfma_f32_16x16x32_bf16(af[m], bg[n], acg[m][n], 0, 0, 0);
      }
  }
  const int row0 = blockIdx.y*128 + wr*64 + (lane >> 4)*4;
  const int col0 = blockIdx.x*128 + wc*64 + (lane & 15);
  #pragma unroll
  for (int m = 0; m < 4; m++)
    #pragma unroll
    for (int rr = 0; rr < 4; rr++) {
      size_t ro = (size_t)(row0 + m*16 + rr) * ldc + col0;
      #pragma unroll
      for (int n = 0; n < 4; n++) {
        float av = aca[m][n][rr], gv = acg[m][n][rr];
        Out[ro + n*16] = (__bf16)(av * gv / (1.f + __expf(-gv)));
      }
    }
}

// ---------------- fused attention: one wave per (b, h) ----------------
__global__ __launch_bounds__(256) void attn_kernel(
    const __bf16* __restrict__ qraw, const __bf16* __restrict__ kvraw,
    const void* __restrict__ nkv_all, int layer, const void* __restrict__ rel_emb,
    __bf16* __restrict__ ao, const int* __restrict__ flag)
{
  bool b16 = flag[0] != 0;
  int gw = blockIdx.x * 4 + (threadIdx.x >> 6);
  int lane = threadIdx.x & 63;
  int b = gw >> 3, h = gw & 7;
  int d = lane;
  bool rot = d < 32;
  int j2 = d >> 1;
  float inv = __expf(-(float)(2*j2) * (1.f/32.f) * 9.210340371976184f); // ln(10000)

  // hoisted: angles t*inv for t=0..3 shared by q (i) and k (j-1)
  float sn[4], cn[4];
  #pragma unroll
  for (int t2 = 0; t2 < 4; t2++) __sincosf((float)t2 * inv, &sn[t2], &cn[t2]);
  // hoisted: rel-pos biases for this head (bucket = max(i-j,0) in [0,3])
  float rb[4];
  #pragma unroll
  for (int t2 = 0; t2 < 4; t2++) rb[t2] = ldf(rel_emb, (size_t)t2 * 8 + h, b16);

  // q rows: rotary + l2norm (SCALE cancels under l2norm)
  float q[4];
  #pragma unroll
  for (int i = 0; i < 4; i++) {
    float v = (float)qraw[((size_t)(b*NTOK + i)) * DIM + h*DH + d];
    float p = __shfl_xor(v, 1, 64);
    if (rot) v = (d & 1) ? (v*cn[i] + p*sn[i]) : (v*cn[i] - p*sn[i]);
    q[i] = v;
  }
  #pragma unroll
  for (int i = 0; i < 4; i++) {
    float nrm = sqrtf(wave_sum(q[i]*q[i]));
    q[i] = q[i] / fmaxf(nrm, 1e-12f);
  }

  // k (null + 4, rotary on real keys, l2norm on all) and v (null + 4)
  float kk[5], vv[5];
  kk[0] = ldf(nkv_all, (size_t)layer*128 + d, b16);
  vv[0] = ldf(nkv_all, (size_t)layer*128 + 64 + d, b16);
  #pragma unroll
  for (int j = 1; j < 5; j++) {
    const __bf16* base = kvraw + ((size_t)(b*NTOK + j - 1)) * 128;
    float v = (float)base[d];
    vv[j] = (float)base[64 + d];
    float p = __shfl_xor(v, 1, 64);
    if (rot) v = (d & 1) ? (v*cn[j-1] + p*sn[j-1]) : (v*cn[j-1] - p*sn[j-1]);
    kk[j] = v;
  }
  #pragma unroll
  for (int j = 0; j < 5; j++) {
    float nrm = sqrtf(wave_sum(kk[j]*kk[j]));
    kk[j] = kk[j] / fmaxf(nrm, 1e-12f);
  }

  // sim (only unmasked j <= i+1), * SCALE(16), + bias; softmax; out = attn @ v
  #pragma unroll
  for (int i = 0; i < 4; i++) {
    float sim[5];
    #pragma unroll
    for (int j = 0; j < 5; j++) {
      if (j > i + 1) break;
      float p = wave_sum(q[i] * kk[j]);
      sim[j] = p * 16.f + rb[(i - j > 0) ? (i - j) : 0];
    }
    float m = sim[0];
    #pragma unroll
    for (int j = 1; j < 5; j++) { if (j > i + 1) break; m = fmaxf(m, sim[j]); }
    float Z = 0.f, o = 0.f;
    #pragma unroll
    for (int j = 0; j < 5; j++) {
      if (j > i + 1) break;
      float e = __expf(sim[j] - m);
      Z += e; o += e * vv[j];
    }
    ao[((size_t)(b*NTOK + i)) * DIM + h*DH + d] = (__bf16)(o / Z);
  }
}

// ---------------- launch ----------------
extern "C" void kernel_launch(void* const* d_in, const int* in_sizes, int n_in,
                              void* d_out, int out_size, void* d_ws, size_t ws_size,
                              hipStream_t stream) {
  const void* image_embed     = d_in[0];
  const void* text_embed      = d_in[1];
  const int*  timesteps       = (const int*)d_in[2];
  const void* time_table      = d_in[3];
  const void* learned_query   = d_in[4];
  const void* rel_emb         = d_in[5];
  const void* attn_norm_g     = d_in[6];
  const void* Wq              = d_in[7];
  const void* Wkv             = d_in[8];
  const void* null_kv         = d_in[9];
  const void* Wo              = d_in[10];
  const void* attn_out_norm_g = d_in[11];
  const void* ff_norm_g       = d_in[12];
  const void* Wff1            = d_in[13];
  const void* Wff2            = d_in[14];
  const void* final_norm_g    = d_in[15];
  const void* Wproj           = d_in[16];

  if (ws_size < WS_NEED) return;

  char* ws = (char*)d_ws;
  __bf16* wtq  = (__bf16*)(ws + OFF_WTQ);
  __bf16* wtkv = (__bf16*)(ws + OFF_WTKV);
  __bf16* wto  = (__bf16*)(ws + OFF_WTO);
  __bf16* wtf1 = (__bf16*)(ws + OFF_WTF1);
  __bf16* wtf2 = (__bf16*)(ws + OFF_WTF2);
  __bf16* wtp  = (__bf16*)(ws + OFF_WTP);
  float*  x    = (float*) (ws + OFF_X);
  __bf16* h    = (__bf16*)(ws + OFF_H);
  __bf16* qraw = (__bf16*)(ws + OFF_QRAW);  // also y; FF act buffer starts here
  __bf16* kvraw= (__bf16*)(ws + OFF_KV);
  __bf16* ao   = (__bf16*)(ws + OFF_AO);    // attn_out / hlast
  __bf16* act  = (__bf16*)(ws + OFF_QRAW);  // 16384 x 2048 bf16 (67MB, aliases qraw+kv+ao)
  int*    flag = (int*)   (ws + OFF_FLAG);

  detect_dtype<<<1, 256, 0, stream>>>((const unsigned int*)Wq, flag);

  dim3 tb(32, 8);
  transpose_any<<<dim3(16, 16, 12),  tb, 0, stream>>>(Wq,   (u16*)wtq,  512,  512,  flag);
  transpose_any<<<dim3(4,  16, 12),  tb, 0, stream>>>(Wkv,  (u16*)wtkv, 512,  128,  flag);
  transpose_any<<<dim3(16, 16, 12),  tb, 0, stream>>>(Wo,   (u16*)wto,  512,  512,  flag);
  transpose_any<<<dim3(128,16, 12),  tb, 0, stream>>>(Wff1, (u16*)wtf1, 512,  4096, flag);
  transpose_any<<<dim3(16, 64, 12),  tb, 0, stream>>>(Wff2, (u16*)wtf2, 2048, 512,  flag);
  transpose_any<<<dim3(16, 16, 1),   tb, 0, stream>>>(Wproj,(u16*)wtp,  512,  512,  flag);

  build_tokens<<<BATCH, 256, 0, stream>>>(text_embed, image_embed, timesteps, time_table,
                                          learned_query, x, flag);

  for (int l = 0; l < DEPTH; l++) {
    const __bf16* wtq_l  = wtq  + (size_t)l * 512 * 512;
    const __bf16* wtkv_l = wtkv + (size_t)l * 128 * 512;
    const __bf16* wto_l  = wto  + (size_t)l * 512 * 512;
    const __bf16* wtf1_l = wtf1 + (size_t)l * 4096 * 512;
    const __bf16* wtf2_l = wtf2 + (size_t)l * 512 * 2048;

    // attention block
    ln_f32_bf16<<<ROWS, 256, 0, stream>>>(x, attn_norm_g, (size_t)l*DIM, h, flag);
    gemm_bt<0><<<dim3(4, ROWS/128), 256, 0, stream>>>(h, DIM, wtq_l, 512, qraw, DIM, 512, flag);
    gemm_bt<0><<<dim3(1, ROWS/128), 256, 0, stream>>>(h, DIM, wtkv_l, 512, kvraw, 128, 512, flag);
    attn_kernel<<<BATCH*HEADS/4, 256, 0, stream>>>(qraw, kvraw, null_kv, l, rel_emb, ao, flag);
    gemm_bt<0><<<dim3(4, ROWS/128), 256, 0, stream>>>(ao, DIM, wto_l, 512, qraw /*y*/, DIM, 512, flag);
    ln_add_ln<<<ROWS, 256, 0, stream>>>(qraw /*y*/, attn_out_norm_g, (size_t)l*DIM,
                                        ff_norm_g, (size_t)l*DIM, x, h, flag);

    // FF: two M-chunks of 16384 rows; act = 16384 x 2048 bf16 in act buffer
    for (int c = 0; c < 2; c++) {
      const __bf16* hc = h + (size_t)c * 16384 * DIM;
      float*        xc = x + (size_t)c * 16384 * DIM;
      gemm_swiglu<<<dim3(16, 128), 256, 0, stream>>>(hc, DIM, wtf1_l, wtf1_l + (size_t)FFI*512,
                                                     512, act, FFI, 512);
      gemm_bt<1><<<dim3(4, 128), 256, 0, stream>>>(act, FFI, wtf2_l, FFI, xc, DIM, 2048, flag);
    }
  }

  ln_final<<<BATCH, 256, 0, stream>>>(x, final_norm_g, ao /*hlast*/, flag);
  gemm_bt<2><<<dim3(4, BATCH/128), 256, 0, stream>>>(ao, DIM, wtp, 512, d_out, DIM, 512, flag);
}

// Round 4
// 7307.993 us; speedup vs baseline: 1.3513x; 1.1746x over previous
//
#include <hip/hip_runtime.h>

typedef __bf16 bf16x8 __attribute__((ext_vector_type(8)));
typedef __bf16 bf16x2 __attribute__((ext_vector_type(2)));
typedef float  f32x4  __attribute__((ext_vector_type(4)));
typedef unsigned short u16;

// ---------------- constants ----------------
#define BATCH   8192
#define NTOK    4
#define ROWS    (BATCH*NTOK)      // 32768
#define DIM     512
#define HEADS   8
#define DH      64
#define FFI     2048              // FF_INNER
#define DEPTH   12
#define LN_EPS  1e-5f

// ---------------- workspace layout (bytes) ----------------
static const size_t OFF_WQKV = 0;                               // (12, 640, 512) bf16
static const size_t SZ_WQKV  = 12ull*640*512*2;
static const size_t OFF_WTO  = OFF_WQKV + SZ_WQKV;
static const size_t SZ_WTO   = 12ull*512*512*2;
static const size_t OFF_WTF1 = OFF_WTO + SZ_WTO;
static const size_t SZ_WTF1  = 12ull*4096*512*2;
static const size_t OFF_WTF2 = OFF_WTF1 + SZ_WTF1;
static const size_t SZ_WTF2  = 12ull*512*2048*2;
static const size_t OFF_WTP  = OFF_WTF2 + SZ_WTF2;
static const size_t SZ_WTP   = 512ull*512*2;
static const size_t OFF_X    = OFF_WTP + SZ_WTP;                // f32 (32768,512)
static const size_t OFF_H    = OFF_X    + (size_t)ROWS*DIM*4;
static const size_t OFF_QKV  = OFF_H    + (size_t)ROWS*DIM*2;   // (32768,640) bf16; also y; act[0:42MB)
static const size_t OFF_AO   = OFF_QKV  + (size_t)ROWS*640*2;   // attn_out / act cont'd / hlast
static const size_t OFF_FLAG = OFF_AO   + (size_t)ROWS*DIM*2;
static const size_t WS_NEED  = OFF_FLAG + 256;                  // ~266 MB
// FF act buffer (16384 x 2048 bf16 = 67,108,864 B) aliases [OFF_QKV, OFF_QKV+67MB):
// spans qkv(41.9M)+ao(33.5M) = 75.5MB of dead-after-attn space. OK.

// ---------------- helpers ----------------
__device__ __forceinline__ float ldf(const void* p, size_t i, bool b16) {
  return b16 ? (float)((const __bf16*)p)[i] : ((const float*)p)[i];
}

__device__ __forceinline__ void gld_lds16(const void* g, void* l) {
  __builtin_amdgcn_global_load_lds((const __attribute__((address_space(1))) void*)g,
                                   (__attribute__((address_space(3))) void*)l, 16, 0, 0);
}

__device__ __forceinline__ float wave_sum(float v) {
  #pragma unroll
  for (int o = 32; o > 0; o >>= 1) v += __shfl_xor(v, o, 64);
  return v;
}

// 256-thread block reduce of (a,b); barrier-balanced so it is safe to call twice
__device__ __forceinline__ void block_reduce2(float& a, float& b, float* sm) {
  #pragma unroll
  for (int o = 32; o > 0; o >>= 1) { a += __shfl_down(a, o, 64); b += __shfl_down(b, o, 64); }
  int lane = threadIdx.x & 63, w = threadIdx.x >> 6;
  __syncthreads();
  if (lane == 0) { sm[w] = a; sm[4+w] = b; }
  __syncthreads();
  a = sm[0]+sm[1]+sm[2]+sm[3];
  b = sm[4]+sm[5]+sm[6]+sm[7];
}

// T1: bijective XCD-aware block remap (m204). Returns new flat bid.
__device__ __forceinline__ int xcd_swz(int bid, int nwg) {
  int q8 = nwg >> 3, r8 = nwg & 7;
  int xcd = bid & 7, loc = bid >> 3;
  return (xcd < r8 ? xcd * (q8 + 1) : r8 * (q8 + 1) + (xcd - r8) * q8) + loc;
}

// ---------------- dtype detection: 1 block, writes flag (1 = bf16, 0 = fp32) ----------------
__global__ void detect_dtype(const unsigned int* __restrict__ w, int* __restrict__ flag) {
  __shared__ int cnt[4];
  int t = threadIdx.x;
  int c = 0;
  for (int i = t; i < 2048; i += 256) {
    unsigned int v = w[i];
    unsigned int lo = v & 0xFFFFu, hi = v >> 16;
    int elo = (int)((lo >> 7) & 0xFF), ehi = (int)((hi >> 7) & 0xFF);
    bool okl = (lo == 0u) || (elo >= 100 && elo <= 140);
    bool okh = (hi == 0u) || (ehi >= 100 && ehi <= 140);
    if (okl && okh) c++;
  }
  #pragma unroll
  for (int o = 32; o > 0; o >>= 1) c += __shfl_down(c, o, 64);
  if ((t & 63) == 0) cnt[t >> 6] = c;
  __syncthreads();
  if (t == 0) flag[0] = (cnt[0] + cnt[1] + cnt[2] + cnt[3] > 1024) ? 1 : 0;
}

// ---------------- weight transpose (K,N)->(rowoff+N, K) with dtype conversion ----------------
__global__ void transpose_any(const void* __restrict__ in, u16* __restrict__ out,
                              int K, int N, size_t out_zsz, int rowoff,
                              const int* __restrict__ flag) {
  bool b16 = flag[0] != 0;
  __shared__ u16 tile[32][33];
  size_t iboff = (size_t)blockIdx.z * K * N;
  size_t oboff = (size_t)blockIdx.z * out_zsz;
  int n0 = blockIdx.x * 32, k0 = blockIdx.y * 32;
  int tx = threadIdx.x, ty = threadIdx.y;
  #pragma unroll
  for (int r = 0; r < 4; r++) {
    float v = ldf(in, iboff + (size_t)(k0 + ty*4 + r) * N + n0 + tx, b16);
    __bf16 bv = (__bf16)v;
    tile[ty*4+r][tx] = __builtin_bit_cast(u16, bv);
  }
  __syncthreads();
  #pragma unroll
  for (int r = 0; r < 4; r++)
    out[oboff + (size_t)(rowoff + n0 + ty*4 + r) * K + k0 + tx] = tile[tx][ty*4+r];
}

// ---------------- token assembly: x (B,4,512) f32 ----------------
__global__ void build_tokens(const void* __restrict__ text, const void* __restrict__ img,
                             const int* __restrict__ ts, const void* __restrict__ table,
                             const void* __restrict__ lq, float* __restrict__ x,
                             const int* __restrict__ flag) {
  bool b16 = flag[0] != 0;
  int b = blockIdx.x, t = threadIdx.x;
  float* xr = x + (size_t)b * NTOK * DIM;
  int tsb = ts[b];
  for (int e = t; e < DIM; e += 256) {
    xr[e]         = ldf(text,  (size_t)b * DIM + e, b16);
    xr[DIM + e]   = ldf(table, (size_t)tsb * DIM + e, b16);
    xr[2*DIM + e] = ldf(img,   (size_t)b * DIM + e, b16);
    xr[3*DIM + e] = ldf(lq,    (size_t)e, b16);
  }
}

// ---------------- LN: f32 row -> bf16 row ----------------
__global__ void ln_f32_bf16(const float* __restrict__ x, const void* __restrict__ g, size_t goff,
                            __bf16* __restrict__ out, const int* __restrict__ flag) {
  bool b16 = flag[0] != 0;
  __shared__ float sm[8];
  int row = blockIdx.x, t = threadIdx.x;
  float2 v = ((const float2*)(x + (size_t)row * DIM))[t];
  float s = v.x + v.y, s2 = v.x*v.x + v.y*v.y;
  block_reduce2(s, s2, sm);
  float mean = s * (1.f/DIM);
  float var  = s2 * (1.f/DIM) - mean*mean;
  float rs = rsqrtf(var + LN_EPS);
  float g0 = ldf(g, goff + 2*t, b16), g1 = ldf(g, goff + 2*t + 1, b16);
  bf16x2 o2 = { (__bf16)((v.x-mean)*rs*g0), (__bf16)((v.y-mean)*rs*g1) };
  ((bf16x2*)(out + (size_t)row * DIM))[t] = o2;
}

// ---------------- fused: x += LN(y; g1); h = LN(x; g2) ----------------
__global__ void ln_add_ln(const __bf16* __restrict__ y,
                          const void* __restrict__ g1, size_t g1off,
                          const void* __restrict__ g2, size_t g2off,
                          float* __restrict__ x, __bf16* __restrict__ h,
                          const int* __restrict__ flag) {
  bool b16 = flag[0] != 0;
  __shared__ float sm[8];
  int row = blockIdx.x, t = threadIdx.x;
  bf16x2 yv = ((const bf16x2*)(y + (size_t)row * DIM))[t];
  float v0 = (float)yv[0], v1 = (float)yv[1];
  float s = v0 + v1, s2 = v0*v0 + v1*v1;
  block_reduce2(s, s2, sm);
  float mean = s * (1.f/DIM);
  float var  = s2 * (1.f/DIM) - mean*mean;
  float rs = rsqrtf(var + LN_EPS);
  float ga = ldf(g1, g1off + 2*t, b16), gb = ldf(g1, g1off + 2*t + 1, b16);
  float2* xr = (float2*)(x + (size_t)row * DIM);
  float2 xv = xr[t];
  xv.x += (v0-mean)*rs*ga;
  xv.y += (v1-mean)*rs*gb;
  xr[t] = xv;
  float s_  = xv.x + xv.y, s2_ = xv.x*xv.x + xv.y*xv.y;
  block_reduce2(s_, s2_, sm);
  float mean2 = s_ * (1.f/DIM);
  float var2  = s2_ * (1.f/DIM) - mean2*mean2;
  float rs2 = rsqrtf(var2 + LN_EPS);
  float gc = ldf(g2, g2off + 2*t, b16), gd = ldf(g2, g2off + 2*t + 1, b16);
  bf16x2 o2 = { (__bf16)((xv.x-mean2)*rs2*gc), (__bf16)((xv.y-mean2)*rs2*gd) };
  ((bf16x2*)(h + (size_t)row * DIM))[t] = o2;
}

// ---------------- final LN on token 3 rows -> hlast (8192,512) bf16 ----------------
__global__ void ln_final(const float* __restrict__ x, const void* __restrict__ g,
                         __bf16* __restrict__ out, const int* __restrict__ flag) {
  bool b16 = flag[0] != 0;
  __shared__ float sm[8];
  int b = blockIdx.x, t = threadIdx.x;
  int row = b*NTOK + 3;
  float2 v = ((const float2*)(x + (size_t)row * DIM))[t];
  float s = v.x + v.y, s2 = v.x*v.x + v.y*v.y;
  block_reduce2(s, s2, sm);
  float mean = s * (1.f/DIM);
  float var  = s2 * (1.f/DIM) - mean*mean;
  float rs = rsqrtf(var + LN_EPS);
  float g0 = ldf(g, (size_t)2*t, b16), g1 = ldf(g, (size_t)2*t + 1, b16);
  bf16x2 o2 = { (__bf16)((v.x-mean)*rs*g0), (__bf16)((v.y-mean)*rs*g1) };
  ((bf16x2*)(out + (size_t)b * DIM))[t] = o2;
}

// ================= GEMM core: BK=64, T2 swizzled LDS, T1 XCD remap =================
// LDS layout: [row][64] bf16 (128B row stride). Data for logical chunk c of row r
// lives at chunk c ^ (r&7). Staging keeps LDS dest linear; the global SOURCE chunk
// is pre-swizzled (rule #21). Fragment reads apply the same XOR.

// C(M,N) = A(M,K) @ B(N,K)^T. MODE 0: store bf16. MODE 1: += f32. MODE 2: per-flag.
template<int MODE>
__global__ __launch_bounds__(256) void gemm_bt(
    const __bf16* __restrict__ A, int lda,
    const __bf16* __restrict__ B, int ldb,
    void* __restrict__ Cv, int ldc, int K, const int* __restrict__ flag)
{
  __shared__ __bf16 As[128*64];
  __shared__ __bf16 Bs[128*64];
  const int tid = threadIdx.x;
  const int nwg = gridDim.x * gridDim.y;
  const int nb  = xcd_swz(blockIdx.y * gridDim.x + blockIdx.x, nwg);
  const int bx = nb % gridDim.x, by = nb / gridDim.x;
  const int wave = tid >> 6, lane = tid & 63;
  const int wr = wave >> 1, wc = wave & 1;
  const __bf16* Ab = A + (size_t)by * 128 * lda;
  const __bf16* Bb = B + (size_t)bx * 128 * ldb;
  f32x4 acc[4][4] = {};
  const int srow = tid >> 3;                    // 0..31
  const int scs  = ((tid & 7) ^ (srow & 7)) * 8; // pre-swizzled source chunk (elems)
  const int lr = lane & 15, lc = lane >> 4;
  for (int k0 = 0; k0 < K; k0 += 64) {
    __syncthreads();
    #pragma unroll
    for (int s = 0; s < 4; s++) {
      gld_lds16(Ab + (size_t)(s*32 + srow)*lda + k0 + scs, (char*)As + s*4096 + wave*1024);
      gld_lds16(Bb + (size_t)(s*32 + srow)*ldb + k0 + scs, (char*)Bs + s*4096 + wave*1024);
    }
    __syncthreads();
    #pragma unroll
    for (int kk = 0; kk < 2; kk++) {
      bf16x8 af[4], bq[4];
      #pragma unroll
      for (int m = 0; m < 4; m++)
        af[m] = *(const bf16x8*)(As + (wr*64 + m*16 + lr)*64 + (((kk*4 + lc) ^ (lr & 7)) * 8));
      #pragma unroll
      for (int n = 0; n < 4; n++)
        bq[n] = *(const bf16x8*)(Bs + (wc*64 + n*16 + lr)*64 + (((kk*4 + lc) ^ (lr & 7)) * 8));
      #pragma unroll
      for (int m = 0; m < 4; m++)
        #pragma unroll
        for (int n = 0; n < 4; n++)
          acc[m][n] = __builtin_amdgcn_mfma_f32_16x16x32_bf16(af[m], bq[n], acc[m][n], 0, 0, 0);
    }
  }
  const int row0 = by*128 + wr*64 + (lane >> 4)*4;
  const int col0 = bx*128 + wc*64 + (lane & 15);
  if (MODE == 0) {
    __bf16* Cb = (__bf16*)Cv;
    #pragma unroll
    for (int m = 0; m < 4; m++)
      #pragma unroll
      for (int rr = 0; rr < 4; rr++) {
        size_t ro = (size_t)(row0 + m*16 + rr) * ldc + col0;
        #pragma unroll
        for (int n = 0; n < 4; n++) Cb[ro + n*16] = (__bf16)acc[m][n][rr];
      }
  } else if (MODE == 1) {
    float* Xf = (float*)Cv;
    #pragma unroll
    for (int m = 0; m < 4; m++)
      #pragma unroll
      for (int rr = 0; rr < 4; rr++) {
        size_t ro = (size_t)(row0 + m*16 + rr) * ldc + col0;
        #pragma unroll
        for (int n = 0; n < 4; n++) Xf[ro + n*16] += acc[m][n][rr];
      }
  } else {
    bool b16o = flag[0] != 0;
    __bf16* Cb = (__bf16*)Cv;
    float*  Cf = (float*)Cv;
    #pragma unroll
    for (int m = 0; m < 4; m++)
      #pragma unroll
      for (int rr = 0; rr < 4; rr++) {
        size_t ro = (size_t)(row0 + m*16 + rr) * ldc + col0;
        #pragma unroll
        for (int n = 0; n < 4; n++) {
          float val = acc[m][n][rr];
          if (b16o) Cb[ro + n*16] = (__bf16)val; else Cf[ro + n*16] = val;
        }
      }
  }
}

// out = (A@Ba^T) * silu(A@Bg^T), bf16
__global__ __launch_bounds__(256) void gemm_swiglu(
    const __bf16* __restrict__ A, int lda,
    const __bf16* __restrict__ Ba, const __bf16* __restrict__ Bg, int ldb,
    __bf16* __restrict__ Out, int ldc, int K)
{
  __shared__ __bf16 As[128*64];
  __shared__ __bf16 Bsa[128*64];
  __shared__ __bf16 Bsg[128*64];
  const int tid = threadIdx.x;
  const int nwg = gridDim.x * gridDim.y;
  const int nb  = xcd_swz(blockIdx.y * gridDim.x + blockIdx.x, nwg);
  const int bx = nb % gridDim.x, by = nb / gridDim.x;
  const int wave = tid >> 6, lane = tid & 63;
  const int wr = wave >> 1, wc = wave & 1;
  const __bf16* Ab  = A  + (size_t)by * 128 * lda;
  const __bf16* Bab = Ba + (size_t)bx * 128 * ldb;
  const __bf16* Bgb = Bg + (size_t)bx * 128 * ldb;
  f32x4 aca[4][4] = {};
  f32x4 acg[4][4] = {};
  const int srow = tid >> 3;
  const int scs  = ((tid & 7) ^ (srow & 7)) * 8;
  const int lr = lane & 15, lc = lane >> 4;
  for (int k0 = 0; k0 < K; k0 += 64) {
    __syncthreads();
    #pragma unroll
    for (int s = 0; s < 4; s++) {
      gld_lds16(Ab  + (size_t)(s*32 + srow)*lda + k0 + scs, (char*)As  + s*4096 + wave*1024);
      gld_lds16(Bab + (size_t)(s*32 + srow)*ldb + k0 + scs, (char*)Bsa + s*4096 + wave*1024);
      gld_lds16(Bgb + (size_t)(s*32 + srow)*ldb + k0 + scs, (char*)Bsg + s*4096 + wave*1024);
    }
    __syncthreads();
    #pragma unroll
    for (int kk = 0; kk < 2; kk++) {
      const int co = ((kk*4 + lc) ^ (lr & 7)) * 8;
      bf16x8 af[4], ba[4], bg[4];
      #pragma unroll
      for (int m = 0; m < 4; m++) af[m] = *(const bf16x8*)(As  + (wr*64 + m*16 + lr)*64 + co);
      #pragma unroll
      for (int n = 0; n < 4; n++) ba[n] = *(const bf16x8*)(Bsa + (wc*64 + n*16 + lr)*64 + co);
      #pragma unroll
      for (int n = 0; n < 4; n++) bg[n] = *(const bf16x8*)(Bsg + (wc*64 + n*16 + lr)*64 + co);
      #pragma unroll
      for (int m = 0; m < 4; m++)
        #pragma unroll
        for (int n = 0; n < 4; n++) {
          aca[m][n] = __builtin_amdgcn_mfma_f32_16x16x32_bf16(af[m], ba[n], aca[m][n], 0, 0, 0);
          acg[m][n] = __builtin_amdgcn_mfma_f32_16x16x32_bf16(af[m], bg[n], acg[m][n], 0, 0, 0);
        }
    }
  }
  const int row0 = by*128 + wr*64 + (lane >> 4)*4;
  const int col0 = bx*128 + wc*64 + (lane & 15);
  #pragma unroll
  for (int m = 0; m < 4; m++)
    #pragma unroll
    for (int rr = 0; rr < 4; rr++) {
      size_t ro = (size_t)(row0 + m*16 + rr) * ldc + col0;
      #pragma unroll
      for (int n = 0; n < 4; n++) {
        float av = aca[m][n][rr], gv = acg[m][n][rr];
        Out[ro + n*16] = (__bf16)(av * gv / (1.f + __expf(-gv)));
      }
    }
}

// ---------------- fused attention: one wave per (b, h); qkv ld = 640 ----------------
__global__ __launch_bounds__(256) void attn_kernel(
    const __bf16* __restrict__ qkv,
    const void* __restrict__ nkv_all, int layer, const void* __restrict__ rel_emb,
    __bf16* __restrict__ ao, const int* __restrict__ flag)
{
  bool b16 = flag[0] != 0;
  int gw = blockIdx.x * 4 + (threadIdx.x >> 6);
  int lane = threadIdx.x & 63;
  int b = gw >> 3, h = gw & 7;
  int d = lane;
  bool rot = d < 32;
  int j2 = d >> 1;
  float inv = __expf(-(float)(2*j2) * (1.f/32.f) * 9.210340371976184f); // ln(10000)

  float sn[4], cn[4];
  #pragma unroll
  for (int t2 = 0; t2 < 4; t2++) __sincosf((float)t2 * inv, &sn[t2], &cn[t2]);
  float rb[4];
  #pragma unroll
  for (int t2 = 0; t2 < 4; t2++) rb[t2] = ldf(rel_emb, (size_t)t2 * 8 + h, b16);

  float q[4];
  #pragma unroll
  for (int i = 0; i < 4; i++) {
    float v = (float)qkv[((size_t)(b*NTOK + i)) * 640 + h*DH + d];
    float p = __shfl_xor(v, 1, 64);
    if (rot) v = (d & 1) ? (v*cn[i] + p*sn[i]) : (v*cn[i] - p*sn[i]);
    q[i] = v;
  }
  #pragma unroll
  for (int i = 0; i < 4; i++) {
    float nrm = sqrtf(wave_sum(q[i]*q[i]));
    q[i] = q[i] / fmaxf(nrm, 1e-12f);
  }

  float kk[5], vv[5];
  kk[0] = ldf(nkv_all, (size_t)layer*128 + d, b16);
  vv[0] = ldf(nkv_all, (size_t)layer*128 + 64 + d, b16);
  #pragma unroll
  for (int j = 1; j < 5; j++) {
    const __bf16* base = qkv + ((size_t)(b*NTOK + j - 1)) * 640 + 512;
    float v = (float)base[d];
    vv[j] = (float)base[64 + d];
    float p = __shfl_xor(v, 1, 64);
    if (rot) v = (d & 1) ? (v*cn[j-1] + p*sn[j-1]) : (v*cn[j-1] - p*sn[j-1]);
    kk[j] = v;
  }
  #pragma unroll
  for (int j = 0; j < 5; j++) {
    float nrm = sqrtf(wave_sum(kk[j]*kk[j]));
    kk[j] = kk[j] / fmaxf(nrm, 1e-12f);
  }

  #pragma unroll
  for (int i = 0; i < 4; i++) {
    float sim[5];
    #pragma unroll
    for (int j = 0; j < 5; j++) {
      if (j > i + 1) break;
      float p = wave_sum(q[i] * kk[j]);
      sim[j] = p * 16.f + rb[(i - j > 0) ? (i - j) : 0];
    }
    float m = sim[0];
    #pragma unroll
    for (int j = 1; j < 5; j++) { if (j > i + 1) break; m = fmaxf(m, sim[j]); }
    float Z = 0.f, o = 0.f;
    #pragma unroll
    for (int j = 0; j < 5; j++) {
      if (j > i + 1) break;
      float e = __expf(sim[j] - m);
      Z += e; o += e * vv[j];
    }
    ao[((size_t)(b*NTOK + i)) * DIM + h*DH + d] = (__bf16)(o / Z);
  }
}

// ---------------- launch ----------------
extern "C" void kernel_launch(void* const* d_in, const int* in_sizes, int n_in,
                              void* d_out, int out_size, void* d_ws, size_t ws_size,
                              hipStream_t stream) {
  const void* image_embed     = d_in[0];
  const void* text_embed      = d_in[1];
  const int*  timesteps       = (const int*)d_in[2];
  const void* time_table      = d_in[3];
  const void* learned_query   = d_in[4];
  const void* rel_emb         = d_in[5];
  const void* attn_norm_g     = d_in[6];
  const void* Wq              = d_in[7];
  const void* Wkv             = d_in[8];
  const void* null_kv         = d_in[9];
  const void* Wo              = d_in[10];
  const void* attn_out_norm_g = d_in[11];
  const void* ff_norm_g       = d_in[12];
  const void* Wff1            = d_in[13];
  const void* Wff2            = d_in[14];
  const void* final_norm_g    = d_in[15];
  const void* Wproj           = d_in[16];

  if (ws_size < WS_NEED) return;

  char* ws = (char*)d_ws;
  __bf16* wqkv = (__bf16*)(ws + OFF_WQKV);
  __bf16* wto  = (__bf16*)(ws + OFF_WTO);
  __bf16* wtf1 = (__bf16*)(ws + OFF_WTF1);
  __bf16* wtf2 = (__bf16*)(ws + OFF_WTF2);
  __bf16* wtp  = (__bf16*)(ws + OFF_WTP);
  float*  x    = (float*) (ws + OFF_X);
  __bf16* h    = (__bf16*)(ws + OFF_H);
  __bf16* qkv  = (__bf16*)(ws + OFF_QKV);   // also y; FF act buffer starts here
  __bf16* ao   = (__bf16*)(ws + OFF_AO);    // attn_out / hlast
  __bf16* act  = (__bf16*)(ws + OFF_QKV);   // 16384 x 2048 bf16 (67MB)
  int*    flag = (int*)   (ws + OFF_FLAG);

  detect_dtype<<<1, 256, 0, stream>>>((const unsigned int*)Wq, flag);

  dim3 tb(32, 8);
  transpose_any<<<dim3(16, 16, 12),  tb, 0, stream>>>(Wq,   (u16*)wqkv, 512,  512,  640ull*512, 0,   flag);
  transpose_any<<<dim3(4,  16, 12),  tb, 0, stream>>>(Wkv,  (u16*)wqkv, 512,  128,  640ull*512, 512, flag);
  transpose_any<<<dim3(16, 16, 12),  tb, 0, stream>>>(Wo,   (u16*)wto,  512,  512,  512ull*512, 0,   flag);
  transpose_any<<<dim3(128,16, 12),  tb, 0, stream>>>(Wff1, (u16*)wtf1, 512,  4096, 4096ull*512,0,   flag);
  transpose_any<<<dim3(16, 64, 12),  tb, 0, stream>>>(Wff2, (u16*)wtf2, 2048, 512,  512ull*2048,0,   flag);
  transpose_any<<<dim3(16, 16, 1),   tb, 0, stream>>>(Wproj,(u16*)wtp,  512,  512,  512ull*512, 0,   flag);

  build_tokens<<<BATCH, 256, 0, stream>>>(text_embed, image_embed, timesteps, time_table,
                                          learned_query, x, flag);

  for (int l = 0; l < DEPTH; l++) {
    const __bf16* wqkv_l = wqkv + (size_t)l * 640 * 512;
    const __bf16* wto_l  = wto  + (size_t)l * 512 * 512;
    const __bf16* wtf1_l = wtf1 + (size_t)l * 4096 * 512;
    const __bf16* wtf2_l = wtf2 + (size_t)l * 512 * 2048;

    // attention block
    ln_f32_bf16<<<ROWS, 256, 0, stream>>>(x, attn_norm_g, (size_t)l*DIM, h, flag);
    gemm_bt<0><<<dim3(5, ROWS/128), 256, 0, stream>>>(h, DIM, wqkv_l, 512, qkv, 640, 512, flag);
    attn_kernel<<<BATCH*HEADS/4, 256, 0, stream>>>(qkv, null_kv, l, rel_emb, ao, flag);
    gemm_bt<0><<<dim3(4, ROWS/128), 256, 0, stream>>>(ao, DIM, wto_l, 512, qkv /*y*/, DIM, 512, flag);
    ln_add_ln<<<ROWS, 256, 0, stream>>>(qkv /*y*/, attn_out_norm_g, (size_t)l*DIM,
                                        ff_norm_g, (size_t)l*DIM, x, h, flag);

    // FF: two M-chunks of 16384 rows; act = 16384 x 2048 bf16
    for (int c = 0; c < 2; c++) {
      const __bf16* hc = h + (size_t)c * 16384 * DIM;
      float*        xc = x + (size_t)c * 16384 * DIM;
      gemm_swiglu<<<dim3(16, 128), 256, 0, stream>>>(hc, DIM, wtf1_l, wtf1_l + (size_t)FFI*512,
                                                     512, act, FFI, 512);
      gemm_bt<1><<<dim3(4, 128), 256, 0, stream>>>(act, FFI, wtf2_l, FFI, xc, DIM, 2048, flag);
    }
  }

  ln_final<<<BATCH, 256, 0, stream>>>(x, final_norm_g, ao /*hlast*/, flag);
  gemm_bt<2><<<dim3(4, BATCH/128), 256, 0, stream>>>(ao, DIM, wtp, 512, d_out, DIM, 512, flag);
}

// Round 5
// 6172.227 us; speedup vs baseline: 1.5999x; 1.1840x over previous
//
#include <hip/hip_runtime.h>

typedef __bf16 bf16x8 __attribute__((ext_vector_type(8)));
typedef __bf16 bf16x2 __attribute__((ext_vector_type(2)));
typedef float  f32x4  __attribute__((ext_vector_type(4)));
typedef unsigned short u16;

// ---------------- constants ----------------
#define BATCH   8192
#define NTOK    4
#define ROWS    (BATCH*NTOK)      // 32768
#define DIM     512
#define HEADS   8
#define DH      64
#define FFI     2048              // FF_INNER
#define DEPTH   12
#define LN_EPS  1e-5f

// ---------------- workspace layout (bytes) ----------------
static const size_t OFF_WQKV = 0;                               // (12, 640, 512) bf16
static const size_t SZ_WQKV  = 12ull*640*512*2;
static const size_t OFF_WTO  = OFF_WQKV + SZ_WQKV;
static const size_t SZ_WTO   = 12ull*512*512*2;
static const size_t OFF_WTF1 = OFF_WTO + SZ_WTO;                // interleaved layout (12,4096,512)
static const size_t SZ_WTF1  = 12ull*4096*512*2;
static const size_t OFF_WTF2 = OFF_WTF1 + SZ_WTF1;
static const size_t SZ_WTF2  = 12ull*512*2048*2;
static const size_t OFF_WTP  = OFF_WTF2 + SZ_WTF2;
static const size_t SZ_WTP   = 512ull*512*2;
static const size_t OFF_X    = OFF_WTP + SZ_WTP;                // f32 (32768,512)
static const size_t OFF_H    = OFF_X    + (size_t)ROWS*DIM*4;
static const size_t OFF_QKV  = OFF_H    + (size_t)ROWS*DIM*2;   // (32768,640) bf16; also y; act[0:67MB)
static const size_t OFF_AO   = OFF_QKV  + (size_t)ROWS*640*2;   // attn_out / act cont'd / hlast
static const size_t OFF_FLAG = OFF_AO   + (size_t)ROWS*DIM*2;
static const size_t WS_NEED  = OFF_FLAG + 256;                  // ~266 MB
// FF act buffer (16384 x 2048 bf16 = 67,108,864 B) aliases [OFF_QKV, OFF_QKV+67MB):
// spans qkv(41.9M)+ao(33.5M) = 75.5MB of dead-after-attn space. OK.

// ---------------- helpers ----------------
__device__ __forceinline__ float ldf(const void* p, size_t i, bool b16) {
  return b16 ? (float)((const __bf16*)p)[i] : ((const float*)p)[i];
}

__device__ __forceinline__ void gld_lds16(const void* g, void* l) {
  __builtin_amdgcn_global_load_lds((const __attribute__((address_space(1))) void*)g,
                                   (__attribute__((address_space(3))) void*)l, 16, 0, 0);
}

__device__ __forceinline__ float wave_sum(float v) {
  #pragma unroll
  for (int o = 32; o > 0; o >>= 1) v += __shfl_xor(v, o, 64);
  return v;
}

// 256-thread block reduce of (a,b); barrier-balanced so it is safe to call twice
__device__ __forceinline__ void block_reduce2(float& a, float& b, float* sm) {
  #pragma unroll
  for (int o = 32; o > 0; o >>= 1) { a += __shfl_down(a, o, 64); b += __shfl_down(b, o, 64); }
  int lane = threadIdx.x & 63, w = threadIdx.x >> 6;
  __syncthreads();
  if (lane == 0) { sm[w] = a; sm[4+w] = b; }
  __syncthreads();
  a = sm[0]+sm[1]+sm[2]+sm[3];
  b = sm[4]+sm[5]+sm[6]+sm[7];
}

// ---------------- dtype detection: 1 block, writes flag (1 = bf16, 0 = fp32) ----------------
__global__ void detect_dtype(const unsigned int* __restrict__ w, int* __restrict__ flag) {
  __shared__ int cnt[4];
  int t = threadIdx.x;
  int c = 0;
  for (int i = t; i < 2048; i += 256) {
    unsigned int v = w[i];
    unsigned int lo = v & 0xFFFFu, hi = v >> 16;
    int elo = (int)((lo >> 7) & 0xFF), ehi = (int)((hi >> 7) & 0xFF);
    bool okl = (lo == 0u) || (elo >= 100 && elo <= 140);
    bool okh = (hi == 0u) || (ehi >= 100 && ehi <= 140);
    if (okl && okh) c++;
  }
  #pragma unroll
  for (int o = 32; o > 0; o >>= 1) c += __shfl_down(c, o, 64);
  if ((t & 63) == 0) cnt[t >> 6] = c;
  __syncthreads();
  if (t == 0) flag[0] = (cnt[0] + cnt[1] + cnt[2] + cnt[3] > 1024) ? 1 : 0;
}

// ---------------- weight transpose (K,N)->(N,K), optional ff1 interleave ----------------
// mode 0: out row = rowoff + n.  mode 1: swiglu interleave row mapping:
//   n -> s=(n>=2048), n'=n-2048s, R = (n'>>7)*256 + ((n'>>5)&3)*64 + s*32 + (n'&31)
__global__ void transpose_any(const void* __restrict__ in, u16* __restrict__ out,
                              int K, int N, size_t out_zsz, int rowoff, int mode,
                              const int* __restrict__ flag) {
  bool b16 = flag[0] != 0;
  __shared__ u16 tile[32][33];
  size_t iboff = (size_t)blockIdx.z * K * N;
  size_t oboff = (size_t)blockIdx.z * out_zsz;
  int n0 = blockIdx.x * 32, k0 = blockIdx.y * 32;
  int tx = threadIdx.x, ty = threadIdx.y;
  #pragma unroll
  for (int r = 0; r < 4; r++) {
    float v = ldf(in, iboff + (size_t)(k0 + ty*4 + r) * N + n0 + tx, b16);
    __bf16 bv = (__bf16)v;
    tile[ty*4+r][tx] = __builtin_bit_cast(u16, bv);
  }
  __syncthreads();
  int rbase;
  if (mode == 0) rbase = rowoff + n0;
  else {
    int s = (n0 >= 2048) ? 1 : 0;
    int np = n0 - s*2048;
    rbase = (np >> 7)*256 + ((np >> 5) & 3)*64 + s*32;   // n0 % 32 == 0
  }
  #pragma unroll
  for (int r = 0; r < 4; r++)
    out[oboff + (size_t)(rbase + ty*4 + r) * K + k0 + tx] = tile[tx][ty*4+r];
}

// ---------------- token assembly: x (B,4,512) f32 ----------------
__global__ void build_tokens(const void* __restrict__ text, const void* __restrict__ img,
                             const int* __restrict__ ts, const void* __restrict__ table,
                             const void* __restrict__ lq, float* __restrict__ x,
                             const int* __restrict__ flag) {
  bool b16 = flag[0] != 0;
  int b = blockIdx.x, t = threadIdx.x;
  float* xr = x + (size_t)b * NTOK * DIM;
  int tsb = ts[b];
  for (int e = t; e < DIM; e += 256) {
    xr[e]         = ldf(text,  (size_t)b * DIM + e, b16);
    xr[DIM + e]   = ldf(table, (size_t)tsb * DIM + e, b16);
    xr[2*DIM + e] = ldf(img,   (size_t)b * DIM + e, b16);
    xr[3*DIM + e] = ldf(lq,    (size_t)e, b16);
  }
}

// ---------------- LN: f32 row -> bf16 row ----------------
__global__ void ln_f32_bf16(const float* __restrict__ x, const void* __restrict__ g, size_t goff,
                            __bf16* __restrict__ out, const int* __restrict__ flag) {
  bool b16 = flag[0] != 0;
  __shared__ float sm[8];
  int row = blockIdx.x, t = threadIdx.x;
  float2 v = ((const float2*)(x + (size_t)row * DIM))[t];
  float s = v.x + v.y, s2 = v.x*v.x + v.y*v.y;
  block_reduce2(s, s2, sm);
  float mean = s * (1.f/DIM);
  float var  = s2 * (1.f/DIM) - mean*mean;
  float rs = rsqrtf(var + LN_EPS);
  float g0 = ldf(g, goff + 2*t, b16), g1 = ldf(g, goff + 2*t + 1, b16);
  bf16x2 o2 = { (__bf16)((v.x-mean)*rs*g0), (__bf16)((v.y-mean)*rs*g1) };
  ((bf16x2*)(out + (size_t)row * DIM))[t] = o2;
}

// ---------------- fused: x += LN(y; g1); h = LN(x; g2) ----------------
__global__ void ln_add_ln(const __bf16* __restrict__ y,
                          const void* __restrict__ g1, size_t g1off,
                          const void* __restrict__ g2, size_t g2off,
                          float* __restrict__ x, __bf16* __restrict__ h,
                          const int* __restrict__ flag) {
  bool b16 = flag[0] != 0;
  __shared__ float sm[8];
  int row = blockIdx.x, t = threadIdx.x;
  bf16x2 yv = ((const bf16x2*)(y + (size_t)row * DIM))[t];
  float v0 = (float)yv[0], v1 = (float)yv[1];
  float s = v0 + v1, s2 = v0*v0 + v1*v1;
  block_reduce2(s, s2, sm);
  float mean = s * (1.f/DIM);
  float var  = s2 * (1.f/DIM) - mean*mean;
  float rs = rsqrtf(var + LN_EPS);
  float ga = ldf(g1, g1off + 2*t, b16), gb = ldf(g1, g1off + 2*t + 1, b16);
  float2* xr = (float2*)(x + (size_t)row * DIM);
  float2 xv = xr[t];
  xv.x += (v0-mean)*rs*ga;
  xv.y += (v1-mean)*rs*gb;
  xr[t] = xv;
  float s_  = xv.x + xv.y, s2_ = xv.x*xv.x + xv.y*xv.y;
  block_reduce2(s_, s2_, sm);
  float mean2 = s_ * (1.f/DIM);
  float var2  = s2_ * (1.f/DIM) - mean2*mean2;
  float rs2 = rsqrtf(var2 + LN_EPS);
  float gc = ldf(g2, g2off + 2*t, b16), gd = ldf(g2, g2off + 2*t + 1, b16);
  bf16x2 o2 = { (__bf16)((xv.x-mean2)*rs2*gc), (__bf16)((xv.y-mean2)*rs2*gd) };
  ((bf16x2*)(h + (size_t)row * DIM))[t] = o2;
}

// ---------------- final LN on token 3 rows -> hlast (8192,512) bf16 ----------------
__global__ void ln_final(const float* __restrict__ x, const void* __restrict__ g,
                         __bf16* __restrict__ out, const int* __restrict__ flag) {
  bool b16 = flag[0] != 0;
  __shared__ float sm[8];
  int b = blockIdx.x, t = threadIdx.x;
  int row = b*NTOK + 3;
  float2 v = ((const float2*)(x + (size_t)row * DIM))[t];
  float s = v.x + v.y, s2 = v.x*v.x + v.y*v.y;
  block_reduce2(s, s2, sm);
  float mean = s * (1.f/DIM);
  float var  = s2 * (1.f/DIM) - mean*mean;
  float rs = rsqrtf(var + LN_EPS);
  float g0 = ldf(g, (size_t)2*t, b16), g1 = ldf(g, (size_t)2*t + 1, b16);
  bf16x2 o2 = { (__bf16)((v.x-mean)*rs*g0), (__bf16)((v.y-mean)*rs*g1) };
  ((bf16x2*)(out + (size_t)b * DIM))[t] = o2;
}

// ================= 2-phase GEMM (128x128, BK=64, swizzled LDS) =================
// C(M,N) = A(M,K) @ B(N,K)^T. MODE 0: store bf16. MODE 2: store bf16 or f32 per flag.
template<int MODE>
__global__ __launch_bounds__(256) void gemm_bt(
    const __bf16* __restrict__ A, int lda,
    const __bf16* __restrict__ B, int ldb,
    void* __restrict__ Cv, int ldc, int K, const int* __restrict__ flag)
{
  __shared__ __bf16 As[128*64];
  __shared__ __bf16 Bs[128*64];
  const int tid = threadIdx.x;
  const int bx = blockIdx.x, by = blockIdx.y;
  const int wave = tid >> 6, lane = tid & 63;
  const int wr = wave >> 1, wc = wave & 1;
  const __bf16* Ab = A + (size_t)by * 128 * lda;
  const __bf16* Bb = B + (size_t)bx * 128 * ldb;
  f32x4 acc[4][4] = {};
  const int srow = tid >> 3;
  const int scs  = ((tid & 7) ^ (srow & 7)) * 8;
  const int lr = lane & 15, lc = lane >> 4;
  for (int k0 = 0; k0 < K; k0 += 64) {
    __syncthreads();
    #pragma unroll
    for (int s = 0; s < 4; s++) {
      gld_lds16(Ab + (size_t)(s*32 + srow)*lda + k0 + scs, (char*)As + s*4096 + wave*1024);
      gld_lds16(Bb + (size_t)(s*32 + srow)*ldb + k0 + scs, (char*)Bs + s*4096 + wave*1024);
    }
    __syncthreads();
    #pragma unroll
    for (int kk = 0; kk < 2; kk++) {
      bf16x8 af[4], bq[4];
      #pragma unroll
      for (int m = 0; m < 4; m++)
        af[m] = *(const bf16x8*)(As + (wr*64 + m*16 + lr)*64 + (((kk*4 + lc) ^ (lr & 7)) * 8));
      #pragma unroll
      for (int n = 0; n < 4; n++)
        bq[n] = *(const bf16x8*)(Bs + (wc*64 + n*16 + lr)*64 + (((kk*4 + lc) ^ (lr & 7)) * 8));
      #pragma unroll
      for (int m = 0; m < 4; m++)
        #pragma unroll
        for (int n = 0; n < 4; n++)
          acc[m][n] = __builtin_amdgcn_mfma_f32_16x16x32_bf16(af[m], bq[n], acc[m][n], 0, 0, 0);
    }
  }
  const int row0 = by*128 + wr*64 + (lane >> 4)*4;
  const int col0 = bx*128 + wc*64 + (lane & 15);
  if (MODE == 0) {
    __bf16* Cb = (__bf16*)Cv;
    #pragma unroll
    for (int m = 0; m < 4; m++)
      #pragma unroll
      for (int rr = 0; rr < 4; rr++) {
        size_t ro = (size_t)(row0 + m*16 + rr) * ldc + col0;
        #pragma unroll
        for (int n = 0; n < 4; n++) Cb[ro + n*16] = (__bf16)acc[m][n][rr];
      }
  } else {
    bool b16o = flag[0] != 0;
    __bf16* Cb = (__bf16*)Cv;
    float*  Cf = (float*)Cv;
    #pragma unroll
    for (int m = 0; m < 4; m++)
      #pragma unroll
      for (int rr = 0; rr < 4; rr++) {
        size_t ro = (size_t)(row0 + m*16 + rr) * ldc + col0;
        #pragma unroll
        for (int n = 0; n < 4; n++) {
          float val = acc[m][n][rr];
          if (b16o) Cb[ro + n*16] = (__bf16)val; else Cf[ro + n*16] = val;
        }
      }
  }
}

// ================= 8-phase pipelined GEMM (256-row tile, counted vmcnt) =================
// BROWS: B-panel rows per block (= output cols per block pre-epilogue).
// EPI 1: swiglu epilogue on interleaved B (out cols = BROWS/2, bf16)
// EPI 2: f32 accumulate (out cols = BROWS)
// Schedule per iter (2 K-tiles t0=buf0, t1=buf1):
//   ph1-4: compute t0 quadrants; stage units of t1 -> buf1
//   ph5-8: compute t1 quadrants; stage units of t_next -> buf0
//   vmcnt(2) + s_barrier at ph1/ph5 (after issuing that phase's unit) -> prev tile landed
//   raw s_barrier at each phase end (no vmcnt drain - loads stay in flight)
template<int BROWS, int EPI>
__global__ __launch_bounds__(512, 2) void gemm8(
    const __bf16* __restrict__ A, int lda,
    const __bf16* __restrict__ B, int ldb,
    void* __restrict__ Cv, int ldc, int K)
{
  constexpr int UNITS = (BROWS == 256) ? 4 : 3;   // 128-row staging units per K-tile (A0,A1,B0[,B1])
  constexpr int WCN   = (BROWS == 256) ? 4 : 2;   // waves along N
  constexpr int M_FR  = (BROWS == 256) ? 8 : 4;   // m-frags per wave
  constexpr int QM    = M_FR / 4;                 // m-frags per phase
  __shared__ char ldsmem[2][(256 + BROWS) * 128];

  const int tid = threadIdx.x;
  const int wid = tid >> 6, lane = tid & 63;
  const int wr = wid / WCN, wc = wid % WCN;
  const int lr = lane & 15, lc = lane >> 4;
  const int sr = tid >> 3;                        // staging row within 64-row half-unit
  const int cs = ((tid & 7) ^ (sr & 7)) * 8;      // pre-swizzled source chunk (elems)
  const int bx = blockIdx.x, by = blockIdx.y;

  const __bf16* Ab = A + (size_t)by * 256 * lda;
  const __bf16* Bb = B + (size_t)bx * BROWS * ldb;

  f32x4 acc[M_FR][4] = {};
  const int NT = K >> 6;

  char* lds0 = ldsmem[0];
  char* lds1 = ldsmem[1];

  // stage one 128-row unit (16KB) of tile kt into buffer p. u: 0,1 = A halves; 2,3 = B halves.
  auto stage_unit = [&](int p, int kt, int u) {
    char* base = (p ? lds1 : lds0);
    if (u < 2) {
      const __bf16* s = Ab + (size_t)(u*128 + sr) * lda + kt*64 + cs;
      char* d = base + u*16384 + (wid << 10);
      gld_lds16(s, d);
      gld_lds16(s + (size_t)64 * lda, d + 8192);
    } else {
      const __bf16* s = Bb + (size_t)((u-2)*128 + sr) * ldb + kt*64 + cs;
      char* d = base + 32768 + (u-2)*16384 + (wid << 10);
      gld_lds16(s, d);
      gld_lds16(s + (size_t)64 * ldb, d + 8192);
    }
  };

  // prologue: tile 0 -> buf0
  #pragma unroll
  for (int u = 0; u < UNITS; u++) stage_unit(0, 0, u);

  const int NIT = NT >> 1;
  for (int i = 0; i < NIT; i++) {
    const int t1 = 2*i + 1;
    const int t2 = (2*i + 2 < NT) ? (2*i + 2) : 0;   // clamped (keeps vmcnt counts uniform)
    #pragma unroll
    for (int hfl = 0; hfl < 2; hfl++) {
      char* cbase = hfl ? lds1 : lds0;               // compute buffer
      const int sp = hfl ^ 1;                        // staging buffer
      const int st = hfl ? t2 : t1;                  // staging tile
      bf16x8 bfr[4][2];
      #pragma unroll
      for (int q = 0; q < 4; q++) {
        if (q < UNITS) stage_unit(sp, st, q);
        if (q == 0) {
          asm volatile("s_waitcnt vmcnt(2)" ::: "memory");
          asm volatile("s_barrier" ::: "memory");
          #pragma unroll
          for (int f = 0; f < 4; f++)
            #pragma unroll
            for (int kk = 0; kk < 2; kk++) {
              int row = wc*64 + f*16 + lr;
              int ch = (kk*4 + lc) ^ (lr & 7);
              bfr[f][kk] = *(const bf16x8*)(cbase + 32768 + row*128 + ch*16);
            }
        }
        bf16x8 afr[QM][2];
        #pragma unroll
        for (int m2 = 0; m2 < QM; m2++)
          #pragma unroll
          for (int kk = 0; kk < 2; kk++) {
            int row = wr*(M_FR*16) + (q*QM + m2)*16 + lr;
            int ch = (kk*4 + lc) ^ (lr & 7);
            afr[m2][kk] = *(const bf16x8*)(cbase + row*128 + ch*16);
          }
        __builtin_amdgcn_s_setprio(1);
        #pragma unroll
        for (int m2 = 0; m2 < QM; m2++)
          #pragma unroll
          for (int n = 0; n < 4; n++)
            #pragma unroll
            for (int kk = 0; kk < 2; kk++)
              acc[q*QM + m2][n] = __builtin_amdgcn_mfma_f32_16x16x32_bf16(
                  afr[m2][kk], bfr[n][kk], acc[q*QM + m2][n], 0, 0, 0);
        __builtin_amdgcn_s_setprio(0);
        asm volatile("s_barrier" ::: "memory");
      }
    }
  }

  if (EPI == 1) {
    // swiglu on interleaved B: frag f in {0,1} = a, f+2 = g, same output col.
    __bf16* Ob = (__bf16*)Cv;
    const int colb = bx*128 + wc*32 + lr;
    const int rowb = by*256 + wr*128 + lc*4;
    #pragma unroll
    for (int m = 0; m < M_FR; m++)
      #pragma unroll
      for (int rr = 0; rr < 4; rr++) {
        size_t ro = (size_t)(rowb + m*16 + rr) * ldc;
        #pragma unroll
        for (int fa = 0; fa < 2; fa++) {
          float a = acc[m][fa][rr], g = acc[m][fa+2][rr];
          Ob[ro + colb + fa*16] = (__bf16)(a * g / (1.f + __expf(-g)));
        }
      }
  } else {
    float* Xf = (float*)Cv;
    const int colb = bx*BROWS + wc*64 + lr;
    const int rowb = by*256 + wr*(M_FR*16) + lc*4;
    #pragma unroll
    for (int m = 0; m < M_FR; m++)
      #pragma unroll
      for (int rr = 0; rr < 4; rr++) {
        size_t ro = (size_t)(rowb + m*16 + rr) * ldc;
        #pragma unroll
        for (int n = 0; n < 4; n++) Xf[ro + colb + n*16] += acc[m][n][rr];
      }
  }
}

// ---------------- fused attention: one wave per (b, h); qkv ld = 640 ----------------
__global__ __launch_bounds__(256) void attn_kernel(
    const __bf16* __restrict__ qkv,
    const void* __restrict__ nkv_all, int layer, const void* __restrict__ rel_emb,
    __bf16* __restrict__ ao, const int* __restrict__ flag)
{
  bool b16 = flag[0] != 0;
  int gw = blockIdx.x * 4 + (threadIdx.x >> 6);
  int lane = threadIdx.x & 63;
  int b = gw >> 3, h = gw & 7;
  int d = lane;
  bool rot = d < 32;
  int j2 = d >> 1;
  float inv = __expf(-(float)(2*j2) * (1.f/32.f) * 9.210340371976184f); // ln(10000)

  float sn[4], cn[4];
  #pragma unroll
  for (int t2 = 0; t2 < 4; t2++) __sincosf((float)t2 * inv, &sn[t2], &cn[t2]);
  float rb[4];
  #pragma unroll
  for (int t2 = 0; t2 < 4; t2++) rb[t2] = ldf(rel_emb, (size_t)t2 * 8 + h, b16);

  float q[4];
  #pragma unroll
  for (int i = 0; i < 4; i++) {
    float v = (float)qkv[((size_t)(b*NTOK + i)) * 640 + h*DH + d];
    float p = __shfl_xor(v, 1, 64);
    if (rot) v = (d & 1) ? (v*cn[i] + p*sn[i]) : (v*cn[i] - p*sn[i]);
    q[i] = v;
  }
  #pragma unroll
  for (int i = 0; i < 4; i++) {
    float nrm = sqrtf(wave_sum(q[i]*q[i]));
    q[i] = q[i] / fmaxf(nrm, 1e-12f);
  }

  float kk[5], vv[5];
  kk[0] = ldf(nkv_all, (size_t)layer*128 + d, b16);
  vv[0] = ldf(nkv_all, (size_t)layer*128 + 64 + d, b16);
  #pragma unroll
  for (int j = 1; j < 5; j++) {
    const __bf16* base = qkv + ((size_t)(b*NTOK + j - 1)) * 640 + 512;
    float v = (float)base[d];
    vv[j] = (float)base[64 + d];
    float p = __shfl_xor(v, 1, 64);
    if (rot) v = (d & 1) ? (v*cn[j-1] + p*sn[j-1]) : (v*cn[j-1] - p*sn[j-1]);
    kk[j] = v;
  }
  #pragma unroll
  for (int j = 0; j < 5; j++) {
    float nrm = sqrtf(wave_sum(kk[j]*kk[j]));
    kk[j] = kk[j] / fmaxf(nrm, 1e-12f);
  }

  #pragma unroll
  for (int i = 0; i < 4; i++) {
    float sim[5];
    #pragma unroll
    for (int j = 0; j < 5; j++) {
      if (j > i + 1) break;
      float p = wave_sum(q[i] * kk[j]);
      sim[j] = p * 16.f + rb[(i - j > 0) ? (i - j) : 0];
    }
    float m = sim[0];
    #pragma unroll
    for (int j = 1; j < 5; j++) { if (j > i + 1) break; m = fmaxf(m, sim[j]); }
    float Z = 0.f, o = 0.f;
    #pragma unroll
    for (int j = 0; j < 5; j++) {
      if (j > i + 1) break;
      float e = __expf(sim[j] - m);
      Z += e; o += e * vv[j];
    }
    ao[((size_t)(b*NTOK + i)) * DIM + h*DH + d] = (__bf16)(o / Z);
  }
}

// ---------------- launch ----------------
extern "C" void kernel_launch(void* const* d_in, const int* in_sizes, int n_in,
                              void* d_out, int out_size, void* d_ws, size_t ws_size,
                              hipStream_t stream) {
  const void* image_embed     = d_in[0];
  const void* text_embed      = d_in[1];
  const int*  timesteps       = (const int*)d_in[2];
  const void* time_table      = d_in[3];
  const void* learned_query   = d_in[4];
  const void* rel_emb         = d_in[5];
  const void* attn_norm_g     = d_in[6];
  const void* Wq              = d_in[7];
  const void* Wkv             = d_in[8];
  const void* null_kv         = d_in[9];
  const void* Wo              = d_in[10];
  const void* attn_out_norm_g = d_in[11];
  const void* ff_norm_g       = d_in[12];
  const void* Wff1            = d_in[13];
  const void* Wff2            = d_in[14];
  const void* final_norm_g    = d_in[15];
  const void* Wproj           = d_in[16];

  if (ws_size < WS_NEED) return;

  char* ws = (char*)d_ws;
  __bf16* wqkv = (__bf16*)(ws + OFF_WQKV);
  __bf16* wto  = (__bf16*)(ws + OFF_WTO);
  __bf16* wtf1 = (__bf16*)(ws + OFF_WTF1);   // interleaved
  __bf16* wtf2 = (__bf16*)(ws + OFF_WTF2);
  __bf16* wtp  = (__bf16*)(ws + OFF_WTP);
  float*  x    = (float*) (ws + OFF_X);
  __bf16* h    = (__bf16*)(ws + OFF_H);
  __bf16* qkv  = (__bf16*)(ws + OFF_QKV);   // also y; FF act buffer starts here
  __bf16* ao   = (__bf16*)(ws + OFF_AO);    // attn_out / hlast
  __bf16* act  = (__bf16*)(ws + OFF_QKV);   // 16384 x 2048 bf16 (67MB)
  int*    flag = (int*)   (ws + OFF_FLAG);

  detect_dtype<<<1, 256, 0, stream>>>((const unsigned int*)Wq, flag);

  dim3 tb(32, 8);
  transpose_any<<<dim3(16, 16, 12),  tb, 0, stream>>>(Wq,   (u16*)wqkv, 512,  512,  640ull*512, 0,   0, flag);
  transpose_any<<<dim3(4,  16, 12),  tb, 0, stream>>>(Wkv,  (u16*)wqkv, 512,  128,  640ull*512, 512, 0, flag);
  transpose_any<<<dim3(16, 16, 12),  tb, 0, stream>>>(Wo,   (u16*)wto,  512,  512,  512ull*512, 0,   0, flag);
  transpose_any<<<dim3(128,16, 12),  tb, 0, stream>>>(Wff1, (u16*)wtf1, 512,  4096, 4096ull*512,0,   1, flag);
  transpose_any<<<dim3(16, 64, 12),  tb, 0, stream>>>(Wff2, (u16*)wtf2, 2048, 512,  512ull*2048,0,   0, flag);
  transpose_any<<<dim3(16, 16, 1),   tb, 0, stream>>>(Wproj,(u16*)wtp,  512,  512,  512ull*512, 0,   0, flag);

  build_tokens<<<BATCH, 256, 0, stream>>>(text_embed, image_embed, timesteps, time_table,
                                          learned_query, x, flag);

  for (int l = 0; l < DEPTH; l++) {
    const __bf16* wqkv_l = wqkv + (size_t)l * 640 * 512;
    const __bf16* wto_l  = wto  + (size_t)l * 512 * 512;
    const __bf16* wtf1_l = wtf1 + (size_t)l * 4096 * 512;
    const __bf16* wtf2_l = wtf2 + (size_t)l * 512 * 2048;

    // attention block
    ln_f32_bf16<<<ROWS, 256, 0, stream>>>(x, attn_norm_g, (size_t)l*DIM, h, flag);
    gemm_bt<0><<<dim3(5, ROWS/128), 256, 0, stream>>>(h, DIM, wqkv_l, 512, qkv, 640, 512, flag);
    attn_kernel<<<BATCH*HEADS/4, 256, 0, stream>>>(qkv, null_kv, l, rel_emb, ao, flag);
    gemm_bt<0><<<dim3(4, ROWS/128), 256, 0, stream>>>(ao, DIM, wto_l, 512, qkv /*y*/, DIM, 512, flag);
    ln_add_ln<<<ROWS, 256, 0, stream>>>(qkv /*y*/, attn_out_norm_g, (size_t)l*DIM,
                                        ff_norm_g, (size_t)l*DIM, x, h, flag);

    // FF: two M-chunks of 16384 rows; act = 16384 x 2048 bf16
    for (int c = 0; c < 2; c++) {
      const __bf16* hc = h + (size_t)c * 16384 * DIM;
      float*        xc = x + (size_t)c * 16384 * DIM;
      gemm8<256,1><<<dim3(16, 64), 512, 0, stream>>>(hc, DIM, wtf1_l, 512, act, FFI, 512);
      gemm8<128,2><<<dim3(4, 64), 512, 0, stream>>>(act, FFI, wtf2_l, FFI, xc, DIM, 2048);
    }
  }

  ln_final<<<BATCH, 256, 0, stream>>>(x, final_norm_g, ao /*hlast*/, flag);
  gemm_bt<2><<<dim3(4, BATCH/128), 256, 0, stream>>>(ao, DIM, wtp, 512, d_out, DIM, 512, flag);
}

// Round 6
// 5397.974 us; speedup vs baseline: 1.8294x; 1.1434x over previous
//
#include <hip/hip_runtime.h>

typedef __bf16 bf16x8 __attribute__((ext_vector_type(8)));
typedef __bf16 bf16x4 __attribute__((ext_vector_type(4)));
typedef __bf16 bf16x2 __attribute__((ext_vector_type(2)));
typedef float  f32x4  __attribute__((ext_vector_type(4)));
typedef unsigned short u16;

// ---------------- constants ----------------
#define BATCH   8192
#define NTOK    4
#define ROWS    (BATCH*NTOK)      // 32768
#define DIM     512
#define HEADS   8
#define DH      64
#define FFI     2048              // FF_INNER
#define DEPTH   12
#define LN_EPS  1e-5f

// ---------------- workspace layout (bytes) ----------------
static const size_t OFF_WQKV = 0;                               // (12, 640, 512) bf16
static const size_t SZ_WQKV  = 12ull*640*512*2;
static const size_t OFF_WTO  = OFF_WQKV + SZ_WQKV;
static const size_t SZ_WTO   = 12ull*512*512*2;
static const size_t OFF_WTF1 = OFF_WTO + SZ_WTO;                // interleaved layout (12,4096,512)
static const size_t SZ_WTF1  = 12ull*4096*512*2;
static const size_t OFF_WTF2 = OFF_WTF1 + SZ_WTF1;
static const size_t SZ_WTF2  = 12ull*512*2048*2;
static const size_t OFF_WTP  = OFF_WTF2 + SZ_WTF2;
static const size_t SZ_WTP   = 512ull*512*2;
static const size_t OFF_X    = OFF_WTP + SZ_WTP;                // f32 (32768,512)
static const size_t OFF_H    = OFF_X    + (size_t)ROWS*DIM*4;
static const size_t OFF_QKV  = OFF_H    + (size_t)ROWS*DIM*2;   // (32768,640) bf16; also y; act[0:67MB)
static const size_t OFF_AO   = OFF_QKV  + (size_t)ROWS*640*2;   // attn_out / act cont'd / hlast
static const size_t OFF_FLAG = OFF_AO   + (size_t)ROWS*DIM*2;
static const size_t WS_NEED  = OFF_FLAG + 256;                  // ~266 MB
// FF act buffer (16384 x 2048 bf16 = 67,108,864 B) aliases [OFF_QKV, OFF_QKV+67MB):
// spans qkv(41.9M)+ao(33.5M) = 75.5MB of dead-after-attn space. OK.

// ---------------- helpers ----------------
__device__ __forceinline__ float ldf(const void* p, size_t i, bool b16) {
  return b16 ? (float)((const __bf16*)p)[i] : ((const float*)p)[i];
}

__device__ __forceinline__ void gld_lds16(const void* g, void* l) {
  __builtin_amdgcn_global_load_lds((const __attribute__((address_space(1))) void*)g,
                                   (__attribute__((address_space(3))) void*)l, 16, 0, 0);
}

// 16-lane-group sum (xor butterfly, offsets 8..1 stay within the group)
__device__ __forceinline__ float gsum16(float v) {
  #pragma unroll
  for (int o = 8; o > 0; o >>= 1) v += __shfl_xor(v, o, 64);
  return v;
}

// 256-thread block reduce of (a,b); barrier-balanced so it is safe to call twice
__device__ __forceinline__ void block_reduce2(float& a, float& b, float* sm) {
  #pragma unroll
  for (int o = 32; o > 0; o >>= 1) { a += __shfl_down(a, o, 64); b += __shfl_down(b, o, 64); }
  int lane = threadIdx.x & 63, w = threadIdx.x >> 6;
  __syncthreads();
  if (lane == 0) { sm[w] = a; sm[4+w] = b; }
  __syncthreads();
  a = sm[0]+sm[1]+sm[2]+sm[3];
  b = sm[4]+sm[5]+sm[6]+sm[7];
}

// ---------------- dtype detection: 1 block, writes flag (1 = bf16, 0 = fp32) ----------------
__global__ void detect_dtype(const unsigned int* __restrict__ w, int* __restrict__ flag) {
  __shared__ int cnt[4];
  int t = threadIdx.x;
  int c = 0;
  for (int i = t; i < 2048; i += 256) {
    unsigned int v = w[i];
    unsigned int lo = v & 0xFFFFu, hi = v >> 16;
    int elo = (int)((lo >> 7) & 0xFF), ehi = (int)((hi >> 7) & 0xFF);
    bool okl = (lo == 0u) || (elo >= 100 && elo <= 140);
    bool okh = (hi == 0u) || (ehi >= 100 && ehi <= 140);
    if (okl && okh) c++;
  }
  #pragma unroll
  for (int o = 32; o > 0; o >>= 1) c += __shfl_down(c, o, 64);
  if ((t & 63) == 0) cnt[t >> 6] = c;
  __syncthreads();
  if (t == 0) flag[0] = (cnt[0] + cnt[1] + cnt[2] + cnt[3] > 1024) ? 1 : 0;
}

// ---------------- weight transpose (K,N)->(N,K), optional ff1 interleave ----------------
// mode 0: out row = rowoff + n.  mode 1: swiglu interleave row mapping:
//   n -> s=(n>=2048), n'=n-2048s, R = (n'>>7)*256 + ((n'>>5)&3)*64 + s*32 + (n'&31)
__global__ void transpose_any(const void* __restrict__ in, u16* __restrict__ out,
                              int K, int N, size_t out_zsz, int rowoff, int mode,
                              const int* __restrict__ flag) {
  bool b16 = flag[0] != 0;
  __shared__ u16 tile[32][33];
  size_t iboff = (size_t)blockIdx.z * K * N;
  size_t oboff = (size_t)blockIdx.z * out_zsz;
  int n0 = blockIdx.x * 32, k0 = blockIdx.y * 32;
  int tx = threadIdx.x, ty = threadIdx.y;
  #pragma unroll
  for (int r = 0; r < 4; r++) {
    float v = ldf(in, iboff + (size_t)(k0 + ty*4 + r) * N + n0 + tx, b16);
    __bf16 bv = (__bf16)v;
    tile[ty*4+r][tx] = __builtin_bit_cast(u16, bv);
  }
  __syncthreads();
  int rbase;
  if (mode == 0) rbase = rowoff + n0;
  else {
    int s = (n0 >= 2048) ? 1 : 0;
    int np = n0 - s*2048;
    rbase = (np >> 7)*256 + ((np >> 5) & 3)*64 + s*32;   // n0 % 32 == 0
  }
  #pragma unroll
  for (int r = 0; r < 4; r++)
    out[oboff + (size_t)(rbase + ty*4 + r) * K + k0 + tx] = tile[tx][ty*4+r];
}

// ---------------- token assembly: x (B,4,512) f32 ----------------
__global__ void build_tokens(const void* __restrict__ text, const void* __restrict__ img,
                             const int* __restrict__ ts, const void* __restrict__ table,
                             const void* __restrict__ lq, float* __restrict__ x,
                             const int* __restrict__ flag) {
  bool b16 = flag[0] != 0;
  int b = blockIdx.x, t = threadIdx.x;
  float* xr = x + (size_t)b * NTOK * DIM;
  int tsb = ts[b];
  for (int e = t; e < DIM; e += 256) {
    xr[e]         = ldf(text,  (size_t)b * DIM + e, b16);
    xr[DIM + e]   = ldf(table, (size_t)tsb * DIM + e, b16);
    xr[2*DIM + e] = ldf(img,   (size_t)b * DIM + e, b16);
    xr[3*DIM + e] = ldf(lq,    (size_t)e, b16);
  }
}

// ---------------- LN: f32 row -> bf16 row ----------------
__global__ void ln_f32_bf16(const float* __restrict__ x, const void* __restrict__ g, size_t goff,
                            __bf16* __restrict__ out, const int* __restrict__ flag) {
  bool b16 = flag[0] != 0;
  __shared__ float sm[8];
  int row = blockIdx.x, t = threadIdx.x;
  float2 v = ((const float2*)(x + (size_t)row * DIM))[t];
  float s = v.x + v.y, s2 = v.x*v.x + v.y*v.y;
  block_reduce2(s, s2, sm);
  float mean = s * (1.f/DIM);
  float var  = s2 * (1.f/DIM) - mean*mean;
  float rs = rsqrtf(var + LN_EPS);
  float g0 = ldf(g, goff + 2*t, b16), g1 = ldf(g, goff + 2*t + 1, b16);
  bf16x2 o2 = { (__bf16)((v.x-mean)*rs*g0), (__bf16)((v.y-mean)*rs*g1) };
  ((bf16x2*)(out + (size_t)row * DIM))[t] = o2;
}

// ---------------- fused: x += LN(y; g1); h = LN(x; g2) ----------------
__global__ void ln_add_ln(const __bf16* __restrict__ y,
                          const void* __restrict__ g1, size_t g1off,
                          const void* __restrict__ g2, size_t g2off,
                          float* __restrict__ x, __bf16* __restrict__ h,
                          const int* __restrict__ flag) {
  bool b16 = flag[0] != 0;
  __shared__ float sm[8];
  int row = blockIdx.x, t = threadIdx.x;
  bf16x2 yv = ((const bf16x2*)(y + (size_t)row * DIM))[t];
  float v0 = (float)yv[0], v1 = (float)yv[1];
  float s = v0 + v1, s2 = v0*v0 + v1*v1;
  block_reduce2(s, s2, sm);
  float mean = s * (1.f/DIM);
  float var  = s2 * (1.f/DIM) - mean*mean;
  float rs = rsqrtf(var + LN_EPS);
  float ga = ldf(g1, g1off + 2*t, b16), gb = ldf(g1, g1off + 2*t + 1, b16);
  float2* xr = (float2*)(x + (size_t)row * DIM);
  float2 xv = xr[t];
  xv.x += (v0-mean)*rs*ga;
  xv.y += (v1-mean)*rs*gb;
  xr[t] = xv;
  float s_  = xv.x + xv.y, s2_ = xv.x*xv.x + xv.y*xv.y;
  block_reduce2(s_, s2_, sm);
  float mean2 = s_ * (1.f/DIM);
  float var2  = s2_ * (1.f/DIM) - mean2*mean2;
  float rs2 = rsqrtf(var2 + LN_EPS);
  float gc = ldf(g2, g2off + 2*t, b16), gd = ldf(g2, g2off + 2*t + 1, b16);
  bf16x2 o2 = { (__bf16)((xv.x-mean2)*rs2*gc), (__bf16)((xv.y-mean2)*rs2*gd) };
  ((bf16x2*)(h + (size_t)row * DIM))[t] = o2;
}

// ---------------- final LN on token 3 rows -> hlast (8192,512) bf16 ----------------
__global__ void ln_final(const float* __restrict__ x, const void* __restrict__ g,
                         __bf16* __restrict__ out, const int* __restrict__ flag) {
  bool b16 = flag[0] != 0;
  __shared__ float sm[8];
  int b = blockIdx.x, t = threadIdx.x;
  int row = b*NTOK + 3;
  float2 v = ((const float2*)(x + (size_t)row * DIM))[t];
  float s = v.x + v.y, s2 = v.x*v.x + v.y*v.y;
  block_reduce2(s, s2, sm);
  float mean = s * (1.f/DIM);
  float var  = s2 * (1.f/DIM) - mean*mean;
  float rs = rsqrtf(var + LN_EPS);
  float g0 = ldf(g, (size_t)2*t, b16), g1 = ldf(g, (size_t)2*t + 1, b16);
  bf16x2 o2 = { (__bf16)((v.x-mean)*rs*g0), (__bf16)((v.y-mean)*rs*g1) };
  ((bf16x2*)(out + (size_t)b * DIM))[t] = o2;
}

// ================= 8-phase pipelined GEMM (256-row tile, counted vmcnt) =================
// BROWS: B-panel rows per block.
// EPI 0: store bf16 (out cols = BROWS)
// EPI 1: swiglu epilogue on interleaved B (out cols = BROWS/2, bf16)
// EPI 2: f32 accumulate (out cols = BROWS)
// EPI 3: store bf16 or f32 per flag (out cols = BROWS)
template<int BROWS, int EPI>
__global__ __launch_bounds__(512, 2) void gemm8(
    const __bf16* __restrict__ A, int lda,
    const __bf16* __restrict__ B, int ldb,
    void* __restrict__ Cv, int ldc, int K, const int* __restrict__ flag)
{
  constexpr int UNITS = (BROWS == 256) ? 4 : 3;   // 128-row staging units per K-tile (A0,A1,B0[,B1])
  constexpr int WCN   = (BROWS == 256) ? 4 : 2;   // waves along N
  constexpr int M_FR  = (BROWS == 256) ? 8 : 4;   // m-frags per wave
  constexpr int QM    = M_FR / 4;                 // m-frags per phase
  __shared__ char ldsmem[2][(256 + BROWS) * 128];

  const int tid = threadIdx.x;
  const int wid = tid >> 6, lane = tid & 63;
  const int wr = wid / WCN, wc = wid % WCN;
  const int lr = lane & 15, lc = lane >> 4;
  const int sr = tid >> 3;                        // staging row within 64-row half-unit
  const int cs = ((tid & 7) ^ (sr & 7)) * 8;      // pre-swizzled source chunk (elems)
  const int bx = blockIdx.x, by = blockIdx.y;

  const __bf16* Ab = A + (size_t)by * 256 * lda;
  const __bf16* Bb = B + (size_t)bx * BROWS * ldb;

  f32x4 acc[M_FR][4] = {};
  const int NT = K >> 6;

  char* lds0 = ldsmem[0];
  char* lds1 = ldsmem[1];

  // stage one 128-row unit (16KB) of tile kt into buffer p. u: 0,1 = A halves; 2,3 = B halves.
  auto stage_unit = [&](int p, int kt, int u) {
    char* base = (p ? lds1 : lds0);
    if (u < 2) {
      const __bf16* s = Ab + (size_t)(u*128 + sr) * lda + kt*64 + cs;
      char* d = base + u*16384 + (wid << 10);
      gld_lds16(s, d);
      gld_lds16(s + (size_t)64 * lda, d + 8192);
    } else {
      const __bf16* s = Bb + (size_t)((u-2)*128 + sr) * ldb + kt*64 + cs;
      char* d = base + 32768 + (u-2)*16384 + (wid << 10);
      gld_lds16(s, d);
      gld_lds16(s + (size_t)64 * ldb, d + 8192);
    }
  };

  // prologue: tile 0 -> buf0
  #pragma unroll
  for (int u = 0; u < UNITS; u++) stage_unit(0, 0, u);

  const int NIT = NT >> 1;
  for (int i = 0; i < NIT; i++) {
    const int t1 = 2*i + 1;
    const int t2 = (2*i + 2 < NT) ? (2*i + 2) : 0;   // clamped (keeps vmcnt counts uniform)
    #pragma unroll
    for (int hfl = 0; hfl < 2; hfl++) {
      char* cbase = hfl ? lds1 : lds0;               // compute buffer
      const int sp = hfl ^ 1;                        // staging buffer
      const int st = hfl ? t2 : t1;                  // staging tile
      bf16x8 bfr[4][2];
      #pragma unroll
      for (int q = 0; q < 4; q++) {
        if (q < UNITS) stage_unit(sp, st, q);
        if (q == 0) {
          asm volatile("s_waitcnt vmcnt(2)" ::: "memory");
          asm volatile("s_barrier" ::: "memory");
          #pragma unroll
          for (int f = 0; f < 4; f++)
            #pragma unroll
            for (int kk = 0; kk < 2; kk++) {
              int row = wc*64 + f*16 + lr;
              int ch = (kk*4 + lc) ^ (lr & 7);
              bfr[f][kk] = *(const bf16x8*)(cbase + 32768 + row*128 + ch*16);
            }
        }
        bf16x8 afr[QM][2];
        #pragma unroll
        for (int m2 = 0; m2 < QM; m2++)
          #pragma unroll
          for (int kk = 0; kk < 2; kk++) {
            int row = wr*(M_FR*16) + (q*QM + m2)*16 + lr;
            int ch = (kk*4 + lc) ^ (lr & 7);
            afr[m2][kk] = *(const bf16x8*)(cbase + row*128 + ch*16);
          }
        __builtin_amdgcn_s_setprio(1);
        #pragma unroll
        for (int m2 = 0; m2 < QM; m2++)
          #pragma unroll
          for (int n = 0; n < 4; n++)
            #pragma unroll
            for (int kk = 0; kk < 2; kk++)
              acc[q*QM + m2][n] = __builtin_amdgcn_mfma_f32_16x16x32_bf16(
                  afr[m2][kk], bfr[n][kk], acc[q*QM + m2][n], 0, 0, 0);
        __builtin_amdgcn_s_setprio(0);
        asm volatile("s_barrier" ::: "memory");
      }
    }
  }

  if (EPI == 1) {
    // swiglu on interleaved B: frag f in {0,1} = a, f+2 = g, same output col.
    __bf16* Ob = (__bf16*)Cv;
    const int colb = bx*128 + wc*32 + lr;
    const int rowb = by*256 + wr*128 + lc*4;
    #pragma unroll
    for (int m = 0; m < M_FR; m++)
      #pragma unroll
      for (int rr = 0; rr < 4; rr++) {
        size_t ro = (size_t)(rowb + m*16 + rr) * ldc;
        #pragma unroll
        for (int fa = 0; fa < 2; fa++) {
          float a = acc[m][fa][rr], g = acc[m][fa+2][rr];
          Ob[ro + colb + fa*16] = (__bf16)(a * g / (1.f + __expf(-g)));
        }
      }
  } else if (EPI == 2) {
    float* Xf = (float*)Cv;
    const int colb = bx*BROWS + wc*64 + lr;
    const int rowb = by*256 + wr*(M_FR*16) + lc*4;
    #pragma unroll
    for (int m = 0; m < M_FR; m++)
      #pragma unroll
      for (int rr = 0; rr < 4; rr++) {
        size_t ro = (size_t)(rowb + m*16 + rr) * ldc;
        #pragma unroll
        for (int n = 0; n < 4; n++) Xf[ro + colb + n*16] += acc[m][n][rr];
      }
  } else if (EPI == 0) {
    __bf16* Cb = (__bf16*)Cv;
    const int colb = bx*BROWS + wc*64 + lr;
    const int rowb = by*256 + wr*(M_FR*16) + lc*4;
    #pragma unroll
    for (int m = 0; m < M_FR; m++)
      #pragma unroll
      for (int rr = 0; rr < 4; rr++) {
        size_t ro = (size_t)(rowb + m*16 + rr) * ldc;
        #pragma unroll
        for (int n = 0; n < 4; n++) Cb[ro + colb + n*16] = (__bf16)acc[m][n][rr];
      }
  } else {
    bool b16o = flag[0] != 0;
    __bf16* Cb = (__bf16*)Cv;
    float*  Cf = (float*)Cv;
    const int colb = bx*BROWS + wc*64 + lr;
    const int rowb = by*256 + wr*(M_FR*16) + lc*4;
    #pragma unroll
    for (int m = 0; m < M_FR; m++)
      #pragma unroll
      for (int rr = 0; rr < 4; rr++) {
        size_t ro = (size_t)(rowb + m*16 + rr) * ldc;
        #pragma unroll
        for (int n = 0; n < 4; n++) {
          float val = acc[m][n][rr];
          if (b16o) Cb[ro + colb + n*16] = (__bf16)val; else Cf[ro + colb + n*16] = val;
        }
      }
  }
}

// ---------------- fused attention, 16-lane-group layout ----------------
// Each 16-lane group serves one (b,h); lane c holds d = 4c..4c+3 (f32).
// Wave = 4 (b,h) of the SAME b (k/v shared, SIMD-redundant at no cost).
// Block = 256 threads = 16 bh = 2 batches. Grid = BATCH/2.
__global__ __launch_bounds__(256) void attn_kernel(
    const __bf16* __restrict__ qkv,
    const void* __restrict__ nkv_all, int layer, const void* __restrict__ rel_emb,
    __bf16* __restrict__ ao, const int* __restrict__ flag)
{
  bool b16 = flag[0] != 0;
  const int tid = threadIdx.x;
  const int w = tid >> 6, l = tid & 63;
  const int g = l >> 4, c = l & 15;
  const int bh = blockIdx.x * 16 + w * 4 + g;
  const int b = bh >> 3, h = bh & 7;
  const bool rot = (c < 8);   // d = 4c..4c+3 < 32

  // rotary inv freqs for this lane's two (even,odd) pairs: p0 = 2c, p1 = 2c+1
  const float LN1E4_32 = 9.210340371976184f * (1.f/32.f);
  float inv0 = __expf(-(float)(4*c)     * LN1E4_32);
  float inv1 = __expf(-(float)(4*c + 2) * LN1E4_32);
  float cs0[4], sn0[4], cs1[4], sn1[4];
  #pragma unroll
  for (int t = 0; t < 4; t++) {
    __sincosf((float)t * inv0, &sn0[t], &cs0[t]);
    __sincosf((float)t * inv1, &sn1[t], &cs1[t]);
  }
  float rb[4];
  #pragma unroll
  for (int t = 0; t < 4; t++) rb[t] = ldf(rel_emb, (size_t)t * 8 + h, b16);

  // q: 4 rows x 4 comps, rotary + l2norm (SCALE cancels under l2norm)
  float q[4][4];
  #pragma unroll
  for (int i = 0; i < 4; i++) {
    bf16x4 qv = *(const bf16x4*)(qkv + ((size_t)(b*NTOK + i)) * 640 + h*DH + c*4);
    float v0 = (float)qv[0], v1 = (float)qv[1], v2 = (float)qv[2], v3 = (float)qv[3];
    if (rot) {
      float n0 = v0*cs0[i] - v1*sn0[i], n1 = v1*cs0[i] + v0*sn0[i];
      float n2 = v2*cs1[i] - v3*sn1[i], n3 = v3*cs1[i] + v2*sn1[i];
      v0 = n0; v1 = n1; v2 = n2; v3 = n3;
    }
    q[i][0] = v0; q[i][1] = v1; q[i][2] = v2; q[i][3] = v3;
  }
  #pragma unroll
  for (int i = 0; i < 4; i++) {
    float ss = q[i][0]*q[i][0] + q[i][1]*q[i][1] + q[i][2]*q[i][2] + q[i][3]*q[i][3];
    float r = 1.f / fmaxf(sqrtf(gsum16(ss)), 1e-12f);
    #pragma unroll
    for (int e = 0; e < 4; e++) q[i][e] *= r;
  }

  // k (null + 4 real, rotary on real), v (null + 4)
  float kk[5][4], vv[5][4];
  #pragma unroll
  for (int e = 0; e < 4; e++) {
    kk[0][e] = ldf(nkv_all, (size_t)layer*128 + c*4 + e, b16);
    vv[0][e] = ldf(nkv_all, (size_t)layer*128 + 64 + c*4 + e, b16);
  }
  #pragma unroll
  for (int j = 1; j < 5; j++) {
    const __bf16* base = qkv + ((size_t)(b*NTOK + j - 1)) * 640 + 512;
    bf16x4 kv4 = *(const bf16x4*)(base + c*4);
    bf16x4 vv4 = *(const bf16x4*)(base + 64 + c*4);
    float v0 = (float)kv4[0], v1 = (float)kv4[1], v2 = (float)kv4[2], v3 = (float)kv4[3];
    if (rot) {
      int t = j - 1;
      float n0 = v0*cs0[t] - v1*sn0[t], n1 = v1*cs0[t] + v0*sn0[t];
      float n2 = v2*cs1[t] - v3*sn1[t], n3 = v3*cs1[t] + v2*sn1[t];
      v0 = n0; v1 = n1; v2 = n2; v3 = n3;
    }
    kk[j][0] = v0; kk[j][1] = v1; kk[j][2] = v2; kk[j][3] = v3;
    #pragma unroll
    for (int e = 0; e < 4; e++) vv[j][e] = (float)vv4[e];
  }
  #pragma unroll
  for (int j = 0; j < 5; j++) {
    float ss = kk[j][0]*kk[j][0] + kk[j][1]*kk[j][1] + kk[j][2]*kk[j][2] + kk[j][3]*kk[j][3];
    float r = 1.f / fmaxf(sqrtf(gsum16(ss)), 1e-12f);
    #pragma unroll
    for (int e = 0; e < 4; e++) kk[j][e] *= r;
  }

  // sims (j <= i+1), softmax, PV; store 8B per (i)
  #pragma unroll
  for (int i = 0; i < 4; i++) {
    float sim[5];
    #pragma unroll
    for (int j = 0; j < 5; j++) {
      if (j > i + 1) break;
      float pp = q[i][0]*kk[j][0] + q[i][1]*kk[j][1] + q[i][2]*kk[j][2] + q[i][3]*kk[j][3];
      sim[j] = 16.f * gsum16(pp) + rb[(i - j > 0) ? (i - j) : 0];
    }
    float m = sim[0];
    #pragma unroll
    for (int j = 1; j < 5; j++) { if (j > i + 1) break; m = fmaxf(m, sim[j]); }
    float Z = 0.f, o0 = 0.f, o1 = 0.f, o2 = 0.f, o3 = 0.f;
    #pragma unroll
    for (int j = 0; j < 5; j++) {
      if (j > i + 1) break;
      float e = __expf(sim[j] - m);
      Z += e;
      o0 += e * vv[j][0]; o1 += e * vv[j][1]; o2 += e * vv[j][2]; o3 += e * vv[j][3];
    }
    float rz = 1.f / Z;
    bf16x4 ov = { (__bf16)(o0*rz), (__bf16)(o1*rz), (__bf16)(o2*rz), (__bf16)(o3*rz) };
    *(bf16x4*)(ao + ((size_t)(b*NTOK + i)) * DIM + h*DH + c*4) = ov;
  }
}

// ---------------- launch ----------------
extern "C" void kernel_launch(void* const* d_in, const int* in_sizes, int n_in,
                              void* d_out, int out_size, void* d_ws, size_t ws_size,
                              hipStream_t stream) {
  const void* image_embed     = d_in[0];
  const void* text_embed      = d_in[1];
  const int*  timesteps       = (const int*)d_in[2];
  const void* time_table      = d_in[3];
  const void* learned_query   = d_in[4];
  const void* rel_emb         = d_in[5];
  const void* attn_norm_g     = d_in[6];
  const void* Wq              = d_in[7];
  const void* Wkv             = d_in[8];
  const void* null_kv         = d_in[9];
  const void* Wo              = d_in[10];
  const void* attn_out_norm_g = d_in[11];
  const void* ff_norm_g       = d_in[12];
  const void* Wff1            = d_in[13];
  const void* Wff2            = d_in[14];
  const void* final_norm_g    = d_in[15];
  const void* Wproj           = d_in[16];

  if (ws_size < WS_NEED) return;

  char* ws = (char*)d_ws;
  __bf16* wqkv = (__bf16*)(ws + OFF_WQKV);
  __bf16* wto  = (__bf16*)(ws + OFF_WTO);
  __bf16* wtf1 = (__bf16*)(ws + OFF_WTF1);   // interleaved
  __bf16* wtf2 = (__bf16*)(ws + OFF_WTF2);
  __bf16* wtp  = (__bf16*)(ws + OFF_WTP);
  float*  x    = (float*) (ws + OFF_X);
  __bf16* h    = (__bf16*)(ws + OFF_H);
  __bf16* qkv  = (__bf16*)(ws + OFF_QKV);   // also y; FF act buffer starts here
  __bf16* ao   = (__bf16*)(ws + OFF_AO);    // attn_out / hlast
  __bf16* act  = (__bf16*)(ws + OFF_QKV);   // 16384 x 2048 bf16 (67MB)
  int*    flag = (int*)   (ws + OFF_FLAG);

  detect_dtype<<<1, 256, 0, stream>>>((const unsigned int*)Wq, flag);

  dim3 tb(32, 8);
  transpose_any<<<dim3(16, 16, 12),  tb, 0, stream>>>(Wq,   (u16*)wqkv, 512,  512,  640ull*512, 0,   0, flag);
  transpose_any<<<dim3(4,  16, 12),  tb, 0, stream>>>(Wkv,  (u16*)wqkv, 512,  128,  640ull*512, 512, 0, flag);
  transpose_any<<<dim3(16, 16, 12),  tb, 0, stream>>>(Wo,   (u16*)wto,  512,  512,  512ull*512, 0,   0, flag);
  transpose_any<<<dim3(128,16, 12),  tb, 0, stream>>>(Wff1, (u16*)wtf1, 512,  4096, 4096ull*512,0,   1, flag);
  transpose_any<<<dim3(16, 64, 12),  tb, 0, stream>>>(Wff2, (u16*)wtf2, 2048, 512,  512ull*2048,0,   0, flag);
  transpose_any<<<dim3(16, 16, 1),   tb, 0, stream>>>(Wproj,(u16*)wtp,  512,  512,  512ull*512, 0,   0, flag);

  build_tokens<<<BATCH, 256, 0, stream>>>(text_embed, image_embed, timesteps, time_table,
                                          learned_query, x, flag);

  for (int l = 0; l < DEPTH; l++) {
    const __bf16* wqkv_l = wqkv + (size_t)l * 640 * 512;
    const __bf16* wto_l  = wto  + (size_t)l * 512 * 512;
    const __bf16* wtf1_l = wtf1 + (size_t)l * 4096 * 512;
    const __bf16* wtf2_l = wtf2 + (size_t)l * 512 * 2048;

    // attention block
    ln_f32_bf16<<<ROWS, 256, 0, stream>>>(x, attn_norm_g, (size_t)l*DIM, h, flag);
    gemm8<128,0><<<dim3(5, 128), 512, 0, stream>>>(h, DIM, wqkv_l, 512, qkv, 640, 512, flag);
    attn_kernel<<<BATCH/2, 256, 0, stream>>>(qkv, null_kv, l, rel_emb, ao, flag);
    gemm8<128,0><<<dim3(4, 128), 512, 0, stream>>>(ao, DIM, wto_l, 512, qkv /*y*/, DIM, 512, flag);
    ln_add_ln<<<ROWS, 256, 0, stream>>>(qkv /*y*/, attn_out_norm_g, (size_t)l*DIM,
                                        ff_norm_g, (size_t)l*DIM, x, h, flag);

    // FF: two M-chunks of 16384 rows; act = 16384 x 2048 bf16
    for (int c = 0; c < 2; c++) {
      const __bf16* hc = h + (size_t)c * 16384 * DIM;
      float*        xc = x + (size_t)c * 16384 * DIM;
      gemm8<256,1><<<dim3(16, 64), 512, 0, stream>>>(hc, DIM, wtf1_l, 512, act, FFI, 512, flag);
      gemm8<128,2><<<dim3(4, 64), 512, 0, stream>>>(act, FFI, wtf2_l, FFI, xc, DIM, 2048, flag);
    }
  }

  ln_final<<<BATCH, 256, 0, stream>>>(x, final_norm_g, ao /*hlast*/, flag);
  gemm8<128,3><<<dim3(4, 32), 512, 0, stream>>>(ao, DIM, wtp, 512, d_out, DIM, 512, flag);
}